// Round 2
// baseline (2293.423 us; speedup 1.0000x reference)
//
#include <hip/hip_runtime.h>
#include <stdint.h>

#define NH 8
#define NB 8
#define NN 1024
#define ND 128
#define NK 16
#define NF (NB*NN)          // 8192 flat (b,n) rows
#define NORM 0.25f          // 1/sqrt(16)

__device__ __forceinline__ float bf2f(uint16_t u){ return __uint_as_float(((uint32_t)u)<<16); }
__device__ __forceinline__ float lo2f(uint32_t u){ return __uint_as_float(u<<16); }
__device__ __forceinline__ float hi2f(uint32_t u){ return __uint_as_float(u & 0xffff0000u); }
__device__ __forceinline__ uint16_t f2bf(float f){
  uint32_t x = __float_as_uint(f);
  uint32_t r = (x + 0x7fffu + ((x>>16)&1u)) >> 16;   // RNE
  return (uint16_t)r;
}

// ---- dtype detection: are the float inputs fp32 or bf16? ----
// bf16 buffer: low 16 bits of each dword are a bf16 of ~N(0,1) -> exponent
// field in [100,134] with ~99% probability. fp32 buffer: low 16 bits are
// uniform mantissa bits -> ~14% probability. flag=1 means bf16.
__global__ void detect_kernel(const uint32_t* __restrict__ q, int* __restrict__ flag){
  if (threadIdx.x == 0 && blockIdx.x == 0){
    int hits = 0;
    for (int i = 0; i < 256; ++i){
      uint32_t lo = q[i] & 0x7fffu;
      uint32_t e = (lo >> 7) & 0xffu;
      if (e >= 100 && e <= 134) ++hits;
    }
    *flag = (hits >= 128) ? 1 : 0;
  }
}

struct ProjArgs {
  const void* x[8];
  const void* w[8];
};

template<bool F32>
__device__ __forceinline__ float projdot(const void* xv, const void* wv,
                                         int h, int row, int k){
  float acc = 0.f;
  if (F32){
    const float* x = (const float*)xv + (size_t)row * ND;
    const float* w = (const float*)wv + h*(ND*NK) + k;
    #pragma unroll
    for (int d = 0; d < ND; ++d) acc += x[d] * w[d*NK];
  } else {
    const uint16_t* x = (const uint16_t*)xv + (size_t)row * ND;
    const uint16_t* w = (const uint16_t*)wv + h*(ND*NK) + k;
    #pragma unroll
    for (int d = 0; d < ND; ++d) acc += bf2f(x[d]) * bf2f(w[d*NK]);
  }
  return acc;
}

// ws[p][h][row][k] = sum_d x[row][d] * W[h][d][k], stored bf16
__global__ __launch_bounds__(256) void proj_kernel(ProjArgs args, uint16_t* ws,
                                                   const int* __restrict__ flag){
  const int p = blockIdx.z, h = blockIdx.y;
  const int tid = threadIdx.x;
  const int row = blockIdx.x * 16 + (tid >> 4);
  const int k = tid & 15;
  float acc;
  if (*flag) acc = projdot<false>(args.x[p], args.w[p], h, row, k);
  else       acc = projdot<true >(args.x[p], args.w[p], h, row, k);
  ws[(size_t)p * ((size_t)NH*NF*NK) + ((size_t)h*NF + row)*NK + k] = f2bf(acc);
}

#define DOT8(u4, q0i) (lo2f((u4).x)*qv[(q0i)+0] + hi2f((u4).x)*qv[(q0i)+1] + \
                       lo2f((u4).y)*qv[(q0i)+2] + hi2f((u4).y)*qv[(q0i)+3] + \
                       lo2f((u4).z)*qv[(q0i)+4] + hi2f((u4).z)*qv[(q0i)+5] + \
                       lo2f((u4).w)*qv[(q0i)+6] + hi2f((u4).w)*qv[(q0i)+7])

#define ACC8(u4, base) do{ acc[(base)+0]+=p*lo2f((u4).x); acc[(base)+1]+=p*hi2f((u4).x); \
  acc[(base)+2]+=p*lo2f((u4).y); acc[(base)+3]+=p*hi2f((u4).y); \
  acc[(base)+4]+=p*lo2f((u4).z); acc[(base)+5]+=p*hi2f((u4).z); \
  acc[(base)+6]+=p*lo2f((u4).w); acc[(base)+7]+=p*hi2f((u4).w);}while(0)

// one wave per q-row group; K/V for (h,b) staged in LDS bf16, plane-split.
// Q/K/V come from ws (always bf16); heads stored bf16.
template<bool MASKED, bool ADD>
__global__ __launch_bounds__(256) void attn_kernel(
    const uint16_t* __restrict__ Qw, const uint16_t* __restrict__ Kw,
    const uint16_t* __restrict__ Vw, const int* __restrict__ mask,
    uint16_t* __restrict__ outp)
{
  __shared__ uint4 lds[4096];           // 64 KB
  const int hb = blockIdx.y;            // h*8 + b
  const int h = hb >> 3, b = hb & 7;
  const int q0 = blockIdx.x * 64;
  const size_t base = ((size_t)h * NF + (size_t)b * NN) * NK;

  const uint4* ksrc = (const uint4*)(Kw + base);
  const uint4* vsrc = (const uint4*)(Vw + base);
  for (int i = threadIdx.x; i < 2048; i += 256) {
    int pl = (i & 1) * 1024 + (i >> 1);
    lds[pl] = ksrc[i];
    lds[2048 + pl] = vsrc[i];
  }
  __syncthreads();

  const int wave = threadIdx.x >> 6, lane = threadIdx.x & 63;
  for (int it = 0; it < 16; ++it) {
    const int q = q0 + it*4 + wave;
    const uint16_t* qr = Qw + base + (size_t)q * NK;
    float qv[16];
    #pragma unroll
    for (int k = 0; k < 16; ++k) qv[k] = bf2f(qr[k]) * NORM;

    const int* mrow = MASKED ? (mask + (size_t)(b*NN + q) * NN) : nullptr;
    float sc[16];
    #pragma unroll
    for (int i = 0; i < 16; ++i) {
      const int n = i*64 + lane;
      uint4 a = lds[n];
      uint4 c = lds[1024 + n];
      float d = DOT8(a, 0) + DOT8(c, 8);
      if (MASKED && mrow[n] != 0) d = -1e30f;
      sc[i] = d;
    }
    float m = sc[0];
    #pragma unroll
    for (int i = 1; i < 16; ++i) m = fmaxf(m, sc[i]);
    #pragma unroll
    for (int off = 32; off; off >>= 1) m = fmaxf(m, __shfl_xor(m, off, 64));
    float l = 0.f;
    #pragma unroll
    for (int i = 0; i < 16; ++i) { sc[i] = __expf(sc[i] - m); l += sc[i]; }
    #pragma unroll
    for (int off = 32; off; off >>= 1) l += __shfl_xor(l, off, 64);

    float acc[16];
    #pragma unroll
    for (int v = 0; v < 16; ++v) acc[v] = 0.f;
    #pragma unroll
    for (int i = 0; i < 16; ++i) {
      const int n = i*64 + lane;
      uint4 a = lds[2048 + n];
      uint4 c = lds[3072 + n];
      const float p = sc[i];
      ACC8(a, 0); ACC8(c, 8);
    }
    #pragma unroll
    for (int v = 0; v < 16; ++v) {
      #pragma unroll
      for (int off = 32; off; off >>= 1) acc[v] += __shfl_xor(acc[v], off, 64);
    }
    const float invl = 1.0f / l;
    float val = 0.f;
    #pragma unroll
    for (int v = 0; v < 16; ++v) val = (lane == v) ? acc[v] : val;
    if (lane < 16) {
      size_t oidx = base + (size_t)q * NK + lane;
      float r = val * invl;
      if (ADD) r += bf2f(outp[oidx]);
      outp[oidx] = f2bf(r);
    }
  }
}

template<bool F32>
__device__ __forceinline__ float outdot(const uint16_t* hp, const void* wv,
                                        int row, int e){
  float acc = 0.f;
  #pragma unroll
  for (int h = 0; h < NH; ++h) {
    const uint16_t* hr = hp + ((size_t)h*NF + row)*NK;
    if (F32){
      const float* wr = (const float*)wv + h*NK*ND + e;
      #pragma unroll
      for (int v = 0; v < NK; ++v) acc += bf2f(hr[v]) * wr[v*ND];
    } else {
      const uint16_t* wr = (const uint16_t*)wv + h*NK*ND + e;
      #pragma unroll
      for (int v = 0; v < NK; ++v) acc += bf2f(hr[v]) * bf2f(wr[v*ND]);
    }
  }
  return acc;
}

// out[b,q,e] = sum_{h,v} heads[h][row][v] * W[h][v][e]; dual-dtype output
__global__ __launch_bounds__(256) void outproj_kernel(
    const uint16_t* __restrict__ heads_node, const uint16_t* __restrict__ heads_c,
    const void* __restrict__ w_node, const void* __restrict__ w_color,
    void* __restrict__ out, const int* __restrict__ flag)
{
  const int s = blockIdx.y;          // 0 node, 1 color
  const int row = blockIdx.x * 2 + (threadIdx.x >> 7);
  const int e = threadIdx.x & 127;
  const uint16_t* hp = s ? heads_c : heads_node;
  const void* w = s ? w_color : w_node;
  const int isbf = *flag;
  float acc;
  if (isbf) acc = outdot<false>(hp, w, row, e);
  else      acc = outdot<true >(hp, w, row, e);
  const size_t oidx = (size_t)s*((size_t)NF*ND) + (size_t)row*ND + e;
  if (isbf) ((uint16_t*)out)[oidx] = f2bf(acc);
  else      ((float*)out)[oidx] = acc;
}

extern "C" void kernel_launch(void* const* d_in, const int* in_sizes, int n_in,
                              void* d_out, int out_size, void* d_ws, size_t ws_size,
                              hipStream_t stream)
{
  const void* q_n = d_in[0];
  const void* q_c = d_in[1];
  const int* mask = (const int*)d_in[2];
  const void* W[10];
  for (int i = 0; i < 10; ++i) W[i] = d_in[3+i];
  // W[0]=W_query_n W[1]=W_key_nn W[2]=W_val_nn W[3]=W_key_c W[4]=W_val_c
  // W[5]=W_query_c W[6]=W_key_n  W[7]=W_val_n  W[8]=W_out_node W[9]=W_out_color

  uint16_t* ws16 = (uint16_t*)d_ws;
  const size_t PE = (size_t)NH*NF*NK;   // 1,048,576 elements per projection
  uint16_t* Qc  = ws16 + 0*PE;
  uint16_t* Kn  = ws16 + 1*PE;
  uint16_t* Vn  = ws16 + 2*PE;
  uint16_t* Qn  = ws16 + 3*PE;
  uint16_t* Knn = ws16 + 4*PE;
  uint16_t* Vnn = ws16 + 5*PE;
  uint16_t* Knc = ws16 + 6*PE;
  uint16_t* Vnc = ws16 + 7*PE;
  uint16_t* heads_node = ws16 + 8*PE;        // bf16, 2 MB
  uint16_t* heads_c    = ws16 + 9*PE;        // bf16, 2 MB
  int* flag = (int*)(ws16 + 10*PE);          // 1 int at +20 MB

  detect_kernel<<<1, 64, 0, stream>>>((const uint32_t*)q_n, flag);

  ProjArgs pa;
  pa.x[0]=q_c; pa.w[0]=W[5];  // Q_c
  pa.x[1]=q_n; pa.w[1]=W[6];  // K_n
  pa.x[2]=q_n; pa.w[2]=W[7];  // V_n
  pa.x[3]=q_n; pa.w[3]=W[0];  // Q_n
  pa.x[4]=q_n; pa.w[4]=W[1];  // K_nn
  pa.x[5]=q_n; pa.w[5]=W[2];  // V_nn
  pa.x[6]=q_c; pa.w[6]=W[3];  // K_nc
  pa.x[7]=q_c; pa.w[7]=W[4];  // V_nc

  proj_kernel<<<dim3(NF/16, NH, 8), 256, 0, stream>>>(pa, ws16, flag);
  attn_kernel<false,false><<<dim3(16,64), 256, 0, stream>>>(Qc, Kn,  Vn,  nullptr, heads_c);
  attn_kernel<true ,false><<<dim3(16,64), 256, 0, stream>>>(Qn, Knn, Vnn, mask,    heads_node);
  attn_kernel<false,true ><<<dim3(16,64), 256, 0, stream>>>(Qn, Knc, Vnc, mask,    heads_node);
  outproj_kernel<<<dim3(NF/2, 2), 256, 0, stream>>>(heads_node, heads_c, W[8], W[9],
                                                    d_out, flag);
}

// Round 4
// 564.937 us; speedup vs baseline: 4.0596x; 4.0596x over previous
//
#include <hip/hip_runtime.h>
#include <stdint.h>

#define NH 8
#define NB 8
#define NN 1024
#define ND 128
#define NK 16
#define NF (NB*NN)          // 8192 flat (b,n) rows
#define NORM 0.25f          // 1/sqrt(16)

typedef float f32x16 __attribute__((ext_vector_type(16)));
typedef short bf16x8 __attribute__((ext_vector_type(8)));

__device__ __forceinline__ float bf2f(uint16_t u){ return __uint_as_float(((uint32_t)u)<<16); }
__device__ __forceinline__ uint16_t f2bf(float f){
  uint32_t x = __float_as_uint(f);
  uint32_t r = (x + 0x7fffu + ((x>>16)&1u)) >> 16;   // RNE
  return (uint16_t)r;
}

// pack mask bits: packQ[b][qw][n] bit r = mask[b][qw*32+r][n]
__global__ __launch_bounds__(256) void pack_kernel(const int* __restrict__ mask,
                                                   uint32_t* __restrict__ packQ){
  const int n = blockIdx.x*256 + threadIdx.x;   // 0..1023
  const int qw = blockIdx.y;                     // 0..31
  const int b = blockIdx.z;                      // 0..7
  const int* mp = mask + ((size_t)b*NN + qw*32)*NN + n;
  uint32_t w = 0;
  #pragma unroll
  for (int i = 0; i < 32; ++i) w |= (mp[(size_t)i*NN] != 0 ? 1u : 0u) << i;
  packQ[((size_t)b*32 + qw)*NN + n] = w;
}

struct ProjArgs { const float* x[8]; const float* w[8]; };

// fp32 in -> bf16 out. ws[p]: Q/K -> [h][row][k]; V (p=2,5,7) -> VT [hb][k][n]
__global__ __launch_bounds__(256) void proj_kernel(ProjArgs args, uint16_t* ws){
  const int p = blockIdx.z, h = blockIdx.y;
  const int row = blockIdx.x * 16 + (threadIdx.x >> 4);   // b*1024+n
  const int k = threadIdx.x & 15;
  const float* x = args.x[p] + (size_t)row * ND;
  const float* w = args.w[p] + h*(ND*NK) + k;
  float acc = 0.f;
  #pragma unroll
  for (int d = 0; d < ND; ++d) acc += x[d] * w[d*NK];
  const bool tr = (p==2)|(p==5)|(p==7);
  size_t idx;
  if (tr) {
    const int b = row >> 10, n = row & 1023;
    idx = ((size_t)(h*NB + b)*NK + k)*NN + n;
  } else {
    idx = ((size_t)h*NF + row)*NK + k;
  }
  ws[(size_t)p*((size_t)NH*NF*NK) + idx] = f2bf(acc);
}

// MFMA attention. One block = 128 q-rows of one (h,b); wave w owns 32 rows.
// K staged in LDS as 2 half-row planes (stride-16B b128 reads).
// V read from global VT [hb][16][1024] (L2-resident, heavy reuse).
// Two-pass softmax: pass1 row-max, pass2 exp+sum+PV. P round-trips LDS.
template<bool MASKED, bool ADD>
__global__ __launch_bounds__(256) void attn_kernel(
    const uint16_t* __restrict__ Qw, const uint16_t* __restrict__ Kw,
    const uint16_t* __restrict__ VTw, const uint32_t* __restrict__ packQ,
    uint16_t* __restrict__ outp)
{
  __shared__ uint4 kpl[2048];                        // 32 KB: [half][n]
  __shared__ __align__(16) uint16_t plds[4*32*40];   // 10 KB: per-wave P, stride 40
  const int hb = blockIdx.y;
  const int h = hb >> 3, b = hb & 7;
  const size_t base = ((size_t)h*NF + (size_t)b*NN)*NK;

  const uint4* ksrc = (const uint4*)(Kw + base);
  for (int i = threadIdx.x; i < 2048; i += 256)
    kpl[(i & 1)*1024 + (i >> 1)] = ksrc[i];
  __syncthreads();

  const int wave = threadIdx.x >> 6, lane = threadIdx.x & 63;
  const int l5 = lane >> 5, lm = lane & 31;
  const int rbase = l5 * 4;
  const int q0 = blockIdx.x*128 + wave*32;

  const bf16x8 aq = *(const bf16x8*)(Qw + base + (size_t)(q0 + lm)*NK + l5*8);
  const uint32_t* mrow = MASKED ? (packQ + ((size_t)b*32 + (q0>>5))*NN + lm) : nullptr;

  f32x16 Z;
  #pragma unroll
  for (int i = 0; i < 16; ++i) Z[i] = 0.f;

  // ---- pass 1: row max of NORM-unscaled scores ----
  float M[16];
  #pragma unroll
  for (int i = 0; i < 16; ++i) M[i] = -3.0e30f;
  for (int t = 0; t < 32; ++t) {
    const int n0 = t*32;
    bf16x8 bk = *(const bf16x8*)(&kpl[l5*1024 + n0 + lm]);
    f32x16 S = __builtin_amdgcn_mfma_f32_32x32x16_bf16(aq, bk, Z, 0, 0, 0);
    uint32_t mw = MASKED ? mrow[n0] : 0u;
    #pragma unroll
    for (int i = 0; i < 16; ++i) {
      float s = S[i];
      if (MASKED && ((mw >> ((i&3) + 8*(i>>2) + rbase)) & 1u)) s = -3.0e30f;
      M[i] = fmaxf(M[i], s);
    }
  }
  #pragma unroll
  for (int i = 0; i < 16; ++i) {
    #pragma unroll
    for (int off = 16; off; off >>= 1) M[i] = fmaxf(M[i], __shfl_xor(M[i], off, 64));
  }
  float mn[16], L[16];
  #pragma unroll
  for (int i = 0; i < 16; ++i) { mn[i] = M[i]*NORM; L[i] = 0.f; }

  // ---- pass 2: p = exp(s*NORM - mn), accumulate l and O = P·V ----
  f32x16 O = Z;
  uint16_t* pw = plds + wave*(32*40);
  const uint16_t* VTb = VTw + (size_t)hb*(NK*NN);
  for (int t = 0; t < 32; ++t) {
    const int n0 = t*32;
    bf16x8 bk = *(const bf16x8*)(&kpl[l5*1024 + n0 + lm]);
    f32x16 S = __builtin_amdgcn_mfma_f32_32x32x16_bf16(aq, bk, Z, 0, 0, 0);
    uint32_t mw = MASKED ? mrow[n0] : 0u;
    #pragma unroll
    for (int i = 0; i < 16; ++i) {
      const int r = (i&3) + 8*(i>>2) + rbase;
      float p;
      if (MASKED && ((mw >> r) & 1u)) p = 0.f;
      else p = __expf(fmaf(S[i], NORM, -mn[i]));
      L[i] += p;
      pw[r*40 + lm] = f2bf(p);
    }
    // wave-private LDS round-trip: C-layout -> A-layout
    bf16x8 a1 = *(const bf16x8*)(pw + lm*40 + l5*8);
    bf16x8 a2 = *(const bf16x8*)(pw + lm*40 + 16 + l5*8);
    bf16x8 bv1, bv2;
    #pragma unroll
    for (int i = 0; i < 8; ++i) { bv1[i] = 0; bv2[i] = 0; }
    if (lm < 16) {
      const uint16_t* vp = VTb + (size_t)lm*NN + n0 + l5*8;
      bv1 = *(const bf16x8*)(vp);
      bv2 = *(const bf16x8*)(vp + 16);
    }
    O = __builtin_amdgcn_mfma_f32_32x32x16_bf16(a1, bv1, O, 0, 0, 0);
    O = __builtin_amdgcn_mfma_f32_32x32x16_bf16(a2, bv2, O, 0, 0, 0);
  }

  #pragma unroll
  for (int i = 0; i < 16; ++i) {
    #pragma unroll
    for (int off = 16; off; off >>= 1) L[i] += __shfl_xor(L[i], off, 64);
  }

  uint16_t* op = outp + base + (size_t)q0*NK;
  if (lm < 16) {
    #pragma unroll
    for (int i = 0; i < 16; ++i) {
      const int r = (i&3) + 8*(i>>2) + rbase;
      const float invl = (L[i] > 0.f) ? 1.f/L[i] : 0.f;
      float v = O[i] * invl;
      if (ADD) v += bf2f(op[(size_t)r*NK + lm]);
      op[(size_t)r*NK + lm] = f2bf(v);
    }
  }
}

// out[b,q,e] = sum_{h,v} heads[h][row][v] * W[h][v][e]; fp32 out
__global__ __launch_bounds__(256) void outproj_kernel(
    const uint16_t* __restrict__ hn, const uint16_t* __restrict__ hc,
    const float* __restrict__ wn, const float* __restrict__ wc,
    float* __restrict__ out)
{
  const int s = blockIdx.y;          // 0 node, 1 color
  const int row = blockIdx.x * 2 + (threadIdx.x >> 7);
  const int e = threadIdx.x & 127;
  const uint16_t* hp = s ? hc : hn;
  const float* w = s ? wc : wn;
  float acc = 0.f;
  #pragma unroll
  for (int h = 0; h < NH; ++h) {
    const uint16_t* hr = hp + ((size_t)h*NF + row)*NK;
    const float* wr = w + h*NK*ND + e;
    #pragma unroll
    for (int v = 0; v < NK; ++v) acc += bf2f(hr[v]) * wr[v*ND];
  }
  out[(size_t)s*((size_t)NF*ND) + (size_t)row*ND + e] = acc;
}

extern "C" void kernel_launch(void* const* d_in, const int* in_sizes, int n_in,
                              void* d_out, int out_size, void* d_ws, size_t ws_size,
                              hipStream_t stream)
{
  const float* q_n = (const float*)d_in[0];
  const float* q_c = (const float*)d_in[1];
  const int* mask = (const int*)d_in[2];
  const float* W[10];
  for (int i = 0; i < 10; ++i) W[i] = (const float*)d_in[3+i];
  // W[0]=W_query_n W[1]=W_key_nn W[2]=W_val_nn W[3]=W_key_c W[4]=W_val_c
  // W[5]=W_query_c W[6]=W_key_n  W[7]=W_val_n  W[8]=W_out_node W[9]=W_out_color

  uint16_t* ws16 = (uint16_t*)d_ws;
  const size_t PE = (size_t)NH*NF*NK;   // 1,048,576 elements per slot
  uint16_t* Qc   = ws16 + 0*PE;
  uint16_t* Kn   = ws16 + 1*PE;
  uint16_t* VTn  = ws16 + 2*PE;   // transposed [hb][16][1024]
  uint16_t* Qn   = ws16 + 3*PE;
  uint16_t* Knn  = ws16 + 4*PE;
  uint16_t* VTnn = ws16 + 5*PE;
  uint16_t* Knc  = ws16 + 6*PE;
  uint16_t* VTnc = ws16 + 7*PE;
  uint16_t* heads_node = ws16 + 8*PE;
  // slot 9 dual-use: packQ (1 MB) consumed by masked attn, then heads_c
  uint32_t* packQ   = (uint32_t*)(ws16 + 9*PE);
  uint16_t* heads_c = ws16 + 9*PE;

  pack_kernel<<<dim3(4,32,8), 256, 0, stream>>>(mask, packQ);

  ProjArgs pa;
  pa.x[0]=q_c; pa.w[0]=W[5];  // Q_c
  pa.x[1]=q_n; pa.w[1]=W[6];  // K_n
  pa.x[2]=q_n; pa.w[2]=W[7];  // V_n  (transposed)
  pa.x[3]=q_n; pa.w[3]=W[0];  // Q_n
  pa.x[4]=q_n; pa.w[4]=W[1];  // K_nn
  pa.x[5]=q_n; pa.w[5]=W[2];  // V_nn (transposed)
  pa.x[6]=q_c; pa.w[6]=W[3];  // K_nc
  pa.x[7]=q_c; pa.w[7]=W[4];  // V_nc (transposed)
  proj_kernel<<<dim3(NF/16, NH, 8), 256, 0, stream>>>(pa, ws16);

  // masked nn first (uses packQ), then nc (accumulate), then color
  // (whose output overwrites the no-longer-needed packQ slot).
  attn_kernel<true ,false><<<dim3(8,64), 256, 0, stream>>>(Qn, Knn, VTnn, packQ, heads_node);
  attn_kernel<false,true ><<<dim3(8,64), 256, 0, stream>>>(Qn, Knc, VTnc, packQ, heads_node);
  attn_kernel<false,false><<<dim3(8,64), 256, 0, stream>>>(Qc, Kn,  VTn,  packQ, heads_c);

  outproj_kernel<<<dim3(NF/2, 2), 256, 0, stream>>>(heads_node, heads_c, W[8], W[9],
                                                    (float*)d_out);
}

// Round 5
// 246.691 us; speedup vs baseline: 9.2968x; 2.2901x over previous
//
#include <hip/hip_runtime.h>
#include <stdint.h>

#define NH 8
#define NB 8
#define NN 1024
#define ND 128
#define NK 16
#define NF (NB*NN)          // 8192 flat (b,n) rows
#define NORM 0.25f          // 1/sqrt(16)
#define LSTR 136            // LDS row stride (bf16 elems): 272 B = 17*16 B

typedef float f32x16 __attribute__((ext_vector_type(16)));
typedef short bf16x8 __attribute__((ext_vector_type(8)));

__device__ __forceinline__ float bf2f(uint16_t u){ return __uint_as_float(((uint32_t)u)<<16); }
__device__ __forceinline__ uint16_t f2bf(float f){
  uint32_t x = __float_as_uint(f);
  uint32_t r = (x + 0x7fffu + ((x>>16)&1u)) >> 16;   // RNE
  return (uint16_t)r;
}

// pack mask bits: packQ[b][qw][n] bit r = mask[b][qw*32+r][n]
__global__ __launch_bounds__(256) void pack_kernel(const int* __restrict__ mask,
                                                   uint32_t* __restrict__ packQ){
  const int n = blockIdx.x*256 + threadIdx.x;   // 0..1023
  const int qw = blockIdx.y;                     // 0..31
  const int b = blockIdx.z;                      // 0..7
  const int* mp = mask + ((size_t)b*NN + qw*32)*NN + n;
  uint32_t w = 0;
  #pragma unroll
  for (int i = 0; i < 32; ++i) w |= (mp[(size_t)i*NN] != 0 ? 1u : 0u) << i;
  packQ[((size_t)b*32 + qw)*NN + n] = w;
}

struct ProjArgs { const float* x[8]; const float* w[8]; };

// MFMA projection: block = 128 rows x one projection p (128 out cols).
// fp32 x,W in; bf16 out. Q/K -> [h][row][k]; V (p=2,5,7) -> VT [hb][k][n].
__global__ __launch_bounds__(256) void proj_kernel(ProjArgs args, uint16_t* ws){
  __shared__ __align__(16) uint16_t WT[128*LSTR];  // [n=h*16+k][d]
  __shared__ __align__(16) uint16_t S[128*LSTR];   // epilogue staging
  const int p = blockIdx.y;
  const int rb = blockIdx.x;           // row-block of 128
  const int tid = threadIdx.x;

  const float* wsrc = args.w[p];       // [h][d][k]
  #pragma unroll 4
  for (int i = 0; i < 64; ++i) {
    int e = i*256 + tid;               // coalesced
    int h = e >> 11, d = (e >> 4) & 127, k = e & 15;
    WT[(h*16 + k)*LSTR + d] = f2bf(wsrc[e]);
  }
  __syncthreads();

  const int wave = tid >> 6, lane = tid & 63;
  const int l5 = lane >> 5, lm = lane & 31;
  const int r0 = rb*128 + wave*32;
  const float* xrow = args.x[p] + (size_t)(r0 + lm)*ND + l5*8;

  bf16x8 afr[8];
  #pragma unroll
  for (int kt = 0; kt < 8; ++kt) {
    float4 f0 = *(const float4*)(xrow + kt*16);
    float4 f1 = *(const float4*)(xrow + kt*16 + 4);
    bf16x8 a;
    a[0]=f2bf(f0.x); a[1]=f2bf(f0.y); a[2]=f2bf(f0.z); a[3]=f2bf(f0.w);
    a[4]=f2bf(f1.x); a[5]=f2bf(f1.y); a[6]=f2bf(f1.z); a[7]=f2bf(f1.w);
    afr[kt] = a;
  }

  const bool tr = (p==2)|(p==5)|(p==7);
  #pragma unroll
  for (int nt = 0; nt < 4; ++nt) {
    f32x16 acc;
    #pragma unroll
    for (int i = 0; i < 16; ++i) acc[i] = 0.f;
    #pragma unroll
    for (int kt = 0; kt < 8; ++kt) {
      bf16x8 b = *(const bf16x8*)(&WT[(nt*32 + lm)*LSTR + kt*16 + l5*8]);
      acc = __builtin_amdgcn_mfma_f32_32x32x16_bf16(afr[kt], b, acc, 0, 0, 0);
    }
    #pragma unroll
    for (int i = 0; i < 16; ++i) {
      int r = wave*32 + (i&3) + 8*(i>>2) + 4*l5;   // local row 0..127
      int c = nt*32 + lm;
      if (tr) S[c*LSTR + r] = f2bf(acc[i]);
      else    S[r*LSTR + c] = f2bf(acc[i]);
    }
  }
  __syncthreads();

  uint16_t* dst = ws + (size_t)p*((size_t)NH*NF*NK);
  if (!tr) {
    #pragma unroll
    for (int it = 0; it < 8; ++it) {
      int c = it*256 + tid;            // 2048 chunks of 8 elems
      int row = c >> 4, cg = c & 15;
      bf16x8 v = *(const bf16x8*)(&S[row*LSTR + cg*8]);
      int h = cg >> 1, k8 = cg & 1;
      *(bf16x8*)(dst + ((size_t)h*NF + rb*128 + row)*NK + k8*8) = v;
    }
  } else {
    const int b = rb >> 3, nb = (rb & 7)*128;
    #pragma unroll
    for (int it = 0; it < 8; ++it) {
      int c = it*256 + tid;
      int col = c >> 4, ng = c & 15;   // col = h*16+k
      bf16x8 v = *(const bf16x8*)(&S[col*LSTR + ng*8]);
      int h = col >> 4, k = col & 15;
      *(bf16x8*)(dst + ((size_t)(h*NB + b)*NK + k)*NN + nb + ng*8) = v;
    }
  }
}

// MFMA attention. One block = 128 q-rows of one (h,b); wave w owns 32 rows.
// K staged in LDS planes; V from global VT [hb][16][1024].
// Two-pass softmax. heads out layout: [row][h*16+k].
template<bool MASKED, bool ADD>
__global__ __launch_bounds__(256) void attn_kernel(
    const uint16_t* __restrict__ Qw, const uint16_t* __restrict__ Kw,
    const uint16_t* __restrict__ VTw, const uint32_t* __restrict__ packQ,
    uint16_t* __restrict__ outp)
{
  __shared__ uint4 kpl[2048];                        // 32 KB: [half][n]
  __shared__ __align__(16) uint16_t plds[4*32*40];   // 10 KB: per-wave P
  const int hb = blockIdx.y;
  const int h = hb >> 3, b = hb & 7;
  const size_t base = ((size_t)h*NF + (size_t)b*NN)*NK;

  const uint4* ksrc = (const uint4*)(Kw + base);
  for (int i = threadIdx.x; i < 2048; i += 256)
    kpl[(i & 1)*1024 + (i >> 1)] = ksrc[i];
  __syncthreads();

  const int wave = threadIdx.x >> 6, lane = threadIdx.x & 63;
  const int l5 = lane >> 5, lm = lane & 31;
  const int rbase = l5 * 4;
  const int q0 = blockIdx.x*128 + wave*32;

  const bf16x8 aq = *(const bf16x8*)(Qw + base + (size_t)(q0 + lm)*NK + l5*8);
  const uint32_t* mrow = MASKED ? (packQ + ((size_t)b*32 + (q0>>5))*NN + lm) : nullptr;

  f32x16 Z;
  #pragma unroll
  for (int i = 0; i < 16; ++i) Z[i] = 0.f;

  float M[16];
  #pragma unroll
  for (int i = 0; i < 16; ++i) M[i] = -3.0e30f;
  for (int t = 0; t < 32; ++t) {
    const int n0 = t*32;
    bf16x8 bk = *(const bf16x8*)(&kpl[l5*1024 + n0 + lm]);
    f32x16 S = __builtin_amdgcn_mfma_f32_32x32x16_bf16(aq, bk, Z, 0, 0, 0);
    uint32_t mw = MASKED ? mrow[n0] : 0u;
    #pragma unroll
    for (int i = 0; i < 16; ++i) {
      float s = S[i];
      if (MASKED && ((mw >> ((i&3) + 8*(i>>2) + rbase)) & 1u)) s = -3.0e30f;
      M[i] = fmaxf(M[i], s);
    }
  }
  #pragma unroll
  for (int i = 0; i < 16; ++i) {
    #pragma unroll
    for (int off = 16; off; off >>= 1) M[i] = fmaxf(M[i], __shfl_xor(M[i], off, 64));
  }
  float mn[16], L[16];
  #pragma unroll
  for (int i = 0; i < 16; ++i) { mn[i] = M[i]*NORM; L[i] = 0.f; }

  f32x16 O = Z;
  uint16_t* pw = plds + wave*(32*40);
  const uint16_t* VTb = VTw + (size_t)hb*(NK*NN);
  for (int t = 0; t < 32; ++t) {
    const int n0 = t*32;
    bf16x8 bk = *(const bf16x8*)(&kpl[l5*1024 + n0 + lm]);
    f32x16 S = __builtin_amdgcn_mfma_f32_32x32x16_bf16(aq, bk, Z, 0, 0, 0);
    uint32_t mw = MASKED ? mrow[n0] : 0u;
    #pragma unroll
    for (int i = 0; i < 16; ++i) {
      const int r = (i&3) + 8*(i>>2) + rbase;
      float p;
      if (MASKED && ((mw >> r) & 1u)) p = 0.f;
      else p = __expf(fmaf(S[i], NORM, -mn[i]));
      L[i] += p;
      pw[r*40 + lm] = f2bf(p);
    }
    bf16x8 a1 = *(const bf16x8*)(pw + lm*40 + l5*8);
    bf16x8 a2 = *(const bf16x8*)(pw + lm*40 + 16 + l5*8);
    bf16x8 bv1, bv2;
    #pragma unroll
    for (int i = 0; i < 8; ++i) { bv1[i] = 0; bv2[i] = 0; }
    if (lm < 16) {
      const uint16_t* vp = VTb + (size_t)lm*NN + n0 + l5*8;
      bv1 = *(const bf16x8*)(vp);
      bv2 = *(const bf16x8*)(vp + 16);
    }
    O = __builtin_amdgcn_mfma_f32_32x32x16_bf16(a1, bv1, O, 0, 0, 0);
    O = __builtin_amdgcn_mfma_f32_32x32x16_bf16(a2, bv2, O, 0, 0, 0);
  }

  #pragma unroll
  for (int i = 0; i < 16; ++i) {
    #pragma unroll
    for (int off = 16; off; off >>= 1) L[i] += __shfl_xor(L[i], off, 64);
  }

  // heads layout [row = b*NN+q][h*16 + k]
  uint16_t* op = outp + ((size_t)b*NN + q0)*128 + h*16;
  if (lm < 16) {
    #pragma unroll
    for (int i = 0; i < 16; ++i) {
      const int r = (i&3) + 8*(i>>2) + rbase;
      const float invl = (L[i] > 0.f) ? 1.f/L[i] : 0.f;
      float v = O[i] * invl;
      if (ADD) v += bf2f(op[(size_t)r*128 + lm]);
      op[(size_t)r*128 + lm] = f2bf(v);
    }
  }
}

// MFMA out-projection: out[row][e] = sum_c heads[row][c] * Wout[c][e]; fp32 out
__global__ __launch_bounds__(256) void outproj_kernel(
    const uint16_t* __restrict__ hn, const uint16_t* __restrict__ hc,
    const float* __restrict__ wn, const float* __restrict__ wc,
    float* __restrict__ out)
{
  __shared__ __align__(16) uint16_t WT[128*LSTR];  // [e][c]
  const int s = blockIdx.y;            // 0 node, 1 color
  const int rb = blockIdx.x;
  const int tid = threadIdx.x;
  const float* wsrc = s ? wc : wn;     // [c=h*16+v][e] row-major 128x128
  #pragma unroll 4
  for (int i = 0; i < 64; ++i) {
    int e = i*256 + tid;
    int c = e >> 7, col = e & 127;
    WT[col*LSTR + c] = f2bf(wsrc[e]);
  }
  __syncthreads();

  const int wave = tid >> 6, lane = tid & 63;
  const int l5 = lane >> 5, lm = lane & 31;
  const int r0 = rb*128 + wave*32;
  const uint16_t* hp = (s ? hc : hn) + (size_t)(r0 + lm)*128 + l5*8;
  bf16x8 afr[8];
  #pragma unroll
  for (int kt = 0; kt < 8; ++kt) afr[kt] = *(const bf16x8*)(hp + kt*16);

  float* dst = out + (size_t)s*((size_t)NF*ND) + (size_t)r0*ND;
  #pragma unroll
  for (int nt = 0; nt < 4; ++nt) {
    f32x16 acc;
    #pragma unroll
    for (int i = 0; i < 16; ++i) acc[i] = 0.f;
    #pragma unroll
    for (int kt = 0; kt < 8; ++kt) {
      bf16x8 b = *(const bf16x8*)(&WT[(nt*32 + lm)*LSTR + kt*16 + l5*8]);
      acc = __builtin_amdgcn_mfma_f32_32x32x16_bf16(afr[kt], b, acc, 0, 0, 0);
    }
    #pragma unroll
    for (int i = 0; i < 16; ++i) {
      int r = (i&3) + 8*(i>>2) + 4*l5;
      dst[(size_t)r*ND + nt*32 + lm] = acc[i];
    }
  }
}

extern "C" void kernel_launch(void* const* d_in, const int* in_sizes, int n_in,
                              void* d_out, int out_size, void* d_ws, size_t ws_size,
                              hipStream_t stream)
{
  const float* q_n = (const float*)d_in[0];
  const float* q_c = (const float*)d_in[1];
  const int* mask = (const int*)d_in[2];
  const float* W[10];
  for (int i = 0; i < 10; ++i) W[i] = (const float*)d_in[3+i];
  // W[0]=W_query_n W[1]=W_key_nn W[2]=W_val_nn W[3]=W_key_c W[4]=W_val_c
  // W[5]=W_query_c W[6]=W_key_n  W[7]=W_val_n  W[8]=W_out_node W[9]=W_out_color

  uint16_t* ws16 = (uint16_t*)d_ws;
  const size_t PE = (size_t)NH*NF*NK;   // 1,048,576 elements per slot
  uint16_t* Qc   = ws16 + 0*PE;
  uint16_t* Kn   = ws16 + 1*PE;
  uint16_t* VTn  = ws16 + 2*PE;   // transposed [hb][16][1024]
  uint16_t* Qn   = ws16 + 3*PE;
  uint16_t* Knn  = ws16 + 4*PE;
  uint16_t* VTnn = ws16 + 5*PE;
  uint16_t* Knc  = ws16 + 6*PE;
  uint16_t* VTnc = ws16 + 7*PE;
  uint16_t* heads_node = ws16 + 8*PE;   // [row][h*16+v] bf16
  // slot 9 dual-use: packQ (1 MB) consumed by masked attn, then heads_c
  uint32_t* packQ   = (uint32_t*)(ws16 + 9*PE);
  uint16_t* heads_c = ws16 + 9*PE;

  pack_kernel<<<dim3(4,32,8), 256, 0, stream>>>(mask, packQ);

  ProjArgs pa;
  pa.x[0]=q_c; pa.w[0]=W[5];  // Q_c
  pa.x[1]=q_n; pa.w[1]=W[6];  // K_n
  pa.x[2]=q_n; pa.w[2]=W[7];  // V_n  (transposed)
  pa.x[3]=q_n; pa.w[3]=W[0];  // Q_n
  pa.x[4]=q_n; pa.w[4]=W[1];  // K_nn
  pa.x[5]=q_n; pa.w[5]=W[2];  // V_nn (transposed)
  pa.x[6]=q_c; pa.w[6]=W[3];  // K_nc
  pa.x[7]=q_c; pa.w[7]=W[4];  // V_nc (transposed)
  proj_kernel<<<dim3(64, 8), 256, 0, stream>>>(pa, ws16);

  // masked nn first (uses packQ), then nc (accumulate), then color
  // (whose output overwrites the no-longer-needed packQ slot).
  attn_kernel<true ,false><<<dim3(8,64), 256, 0, stream>>>(Qn, Knn, VTnn, packQ, heads_node);
  attn_kernel<false,true ><<<dim3(8,64), 256, 0, stream>>>(Qn, Knc, VTnc, packQ, heads_node);
  attn_kernel<false,false><<<dim3(8,64), 256, 0, stream>>>(Qc, Kn,  VTn,  packQ, heads_c);

  outproj_kernel<<<dim3(64, 2), 256, 0, stream>>>(heads_node, heads_c, W[8], W[9],
                                                  (float*)d_out);
}

// Round 6
// 207.085 us; speedup vs baseline: 11.0748x; 1.1913x over previous
//
#include <hip/hip_runtime.h>
#include <stdint.h>

#define NH 8
#define NB 8
#define NN 1024
#define ND 128
#define NK 16
#define NF (NB*NN)          // 8192 flat (b,n) rows
#define NORM 0.25f          // 1/sqrt(16)
#define C2EXP 0.36067376022224085f   // NORM * log2(e)
#define LSTR 136            // LDS row stride (bf16 elems): 272 B = 17*16 B

typedef float f32x16 __attribute__((ext_vector_type(16)));
typedef short bf16x8 __attribute__((ext_vector_type(8)));

__device__ __forceinline__ float bf2f(uint16_t u){ return __uint_as_float(((uint32_t)u)<<16); }
__device__ __forceinline__ uint16_t f2bf(float f){
  uint32_t x = __float_as_uint(f);
  uint32_t r = (x + 0x7fffu + ((x>>16)&1u)) >> 16;   // RNE
  return (uint16_t)r;
}
__device__ __forceinline__ float fast_exp2(float x){
#if __has_builtin(__builtin_amdgcn_exp2f)
  return __builtin_amdgcn_exp2f(x);
#else
  return exp2f(x);
#endif
}

// pack mask n-major: packN[row=b*NN+q][t] bit j = mask[b][q][t*32+j]
__global__ __launch_bounds__(256) void pack_kernel(const int* __restrict__ mask,
                                                   uint32_t* __restrict__ packN){
  const int w = threadIdx.x >> 6, lane = threadIdx.x & 63;
  const int row = blockIdx.x*4 + w;          // 0..8191
  const int* mp = mask + (size_t)row*NN;
  uint32_t* dst = packN + (size_t)row*32;
  for (int wq = 0; wq < 16; ++wq) {
    int v = mp[wq*64 + lane];
    unsigned long long bal = __ballot(v != 0);
    if (lane == 0) { dst[wq*2] = (uint32_t)bal; dst[wq*2+1] = (uint32_t)(bal>>32); }
  }
}

struct ProjArgs { const float* x[8]; const float* w[8]; };

// MFMA projection: block = 128 rows x one projection p (128 out cols).
// fp32 x,W in; bf16 out. Q/K -> [h][row][k]; V (p=2,5,7) -> VT [hb][k][n].
__global__ __launch_bounds__(256) void proj_kernel(ProjArgs args, uint16_t* ws){
  __shared__ __align__(16) uint16_t WT[128*LSTR];  // [n=h*16+k][d]
  __shared__ __align__(16) uint16_t S[128*LSTR];   // epilogue staging
  const int p = blockIdx.y;
  const int rb = blockIdx.x;           // row-block of 128
  const int tid = threadIdx.x;

  const float* wsrc = args.w[p];       // [h][d][k]
  #pragma unroll 4
  for (int i = 0; i < 64; ++i) {
    int e = i*256 + tid;               // coalesced
    int h = e >> 11, d = (e >> 4) & 127, k = e & 15;
    WT[(h*16 + k)*LSTR + d] = f2bf(wsrc[e]);
  }
  __syncthreads();

  const int wave = tid >> 6, lane = tid & 63;
  const int l5 = lane >> 5, lm = lane & 31;
  const int r0 = rb*128 + wave*32;
  const float* xrow = args.x[p] + (size_t)(r0 + lm)*ND + l5*8;

  bf16x8 afr[8];
  #pragma unroll
  for (int kt = 0; kt < 8; ++kt) {
    float4 f0 = *(const float4*)(xrow + kt*16);
    float4 f1 = *(const float4*)(xrow + kt*16 + 4);
    bf16x8 a;
    a[0]=f2bf(f0.x); a[1]=f2bf(f0.y); a[2]=f2bf(f0.z); a[3]=f2bf(f0.w);
    a[4]=f2bf(f1.x); a[5]=f2bf(f1.y); a[6]=f2bf(f1.z); a[7]=f2bf(f1.w);
    afr[kt] = a;
  }

  const bool tr = (p==2)|(p==5)|(p==7);
  #pragma unroll
  for (int nt = 0; nt < 4; ++nt) {
    f32x16 acc;
    #pragma unroll
    for (int i = 0; i < 16; ++i) acc[i] = 0.f;
    #pragma unroll
    for (int kt = 0; kt < 8; ++kt) {
      bf16x8 b = *(const bf16x8*)(&WT[(nt*32 + lm)*LSTR + kt*16 + l5*8]);
      acc = __builtin_amdgcn_mfma_f32_32x32x16_bf16(afr[kt], b, acc, 0, 0, 0);
    }
    #pragma unroll
    for (int i = 0; i < 16; ++i) {
      int r = wave*32 + (i&3) + 8*(i>>2) + 4*l5;   // local row 0..127
      int c = nt*32 + lm;
      if (tr) S[c*LSTR + r] = f2bf(acc[i]);
      else    S[r*LSTR + c] = f2bf(acc[i]);
    }
  }
  __syncthreads();

  uint16_t* dst = ws + (size_t)p*((size_t)NH*NF*NK);
  if (!tr) {
    #pragma unroll
    for (int it = 0; it < 8; ++it) {
      int c = it*256 + tid;            // 2048 chunks of 8 elems
      int row = c >> 4, cg = c & 15;
      bf16x8 v = *(const bf16x8*)(&S[row*LSTR + cg*8]);
      int h = cg >> 1, k8 = cg & 1;
      *(bf16x8*)(dst + ((size_t)h*NF + rb*128 + row)*NK + k8*8) = v;
    }
  } else {
    const int b = rb >> 3, nb = (rb & 7)*128;
    #pragma unroll
    for (int it = 0; it < 8; ++it) {
      int c = it*256 + tid;
      int col = c >> 4, ng = c & 15;   // col = h*16+k
      bf16x8 v = *(const bf16x8*)(&S[col*LSTR + ng*8]);
      int h = col >> 4, k = col & 15;
      *(bf16x8*)(dst + ((size_t)(h*NB + b)*NK + k)*NN + nb + ng*8) = v;
    }
  }
}

// One attention stream over 32 n-tiles. S^T trick: lane = query column.
// No max subtraction (|s*NORM| << 88, softmax is shift-invariant).
template<bool MASKED>
__device__ __forceinline__ void attn_stream(
    const uint4* __restrict__ kplane, bf16x8 aq,
    const uint16_t* __restrict__ VTb, const uint4* __restrict__ pmw4,
    int l5, int lm, f32x16& O, float& L)
{
  f32x16 Z;
  #pragma unroll
  for (int i = 0; i < 16; ++i) Z[i] = 0.f;
  for (int t4 = 0; t4 < 8; ++t4) {
    uint4 mq;
    if (MASKED) mq = pmw4[t4];
    #pragma unroll
    for (int j = 0; j < 4; ++j) {
      const int n0 = (t4*4 + j)*32;
      bf16x8 bk = *(const bf16x8*)(&kplane[l5*1024 + n0 + lm]);
      // S^T tile: operands swapped (A=K rows, B=Q^T) -> lane holds col q=lm
      f32x16 St = __builtin_amdgcn_mfma_f32_32x32x16_bf16(bk, aq, Z, 0, 0, 0);
      uint32_t mws = 0;
      if (MASKED) {
        uint32_t mw = (j==0) ? mq.x : (j==1) ? mq.y : (j==2) ? mq.z : mq.w;
        mws = mw >> (4*l5);
      }
      float p[16];
      #pragma unroll
      for (int i = 0; i < 16; ++i) {
        float arg = St[i] * C2EXP;
        if (MASKED && ((mws >> ((i&3) + 8*(i>>2))) & 1u)) arg = -__builtin_inff();
        float pv = fast_exp2(arg);     // exp2(-inf)=0
        L += pv;
        p[i] = pv;
      }
      // pack p (rows r = (i&3)+8*(i>>2)+4*l5) into bf16 pairs, round-half-up
      uint32_t o[8];
      #pragma unroll
      for (int k = 0; k < 8; ++k) {
        uint32_t lo = __float_as_uint(p[2*k])   + 0x8000u;
        uint32_t hi = __float_as_uint(p[2*k+1]) + 0x8000u;
        o[k] = __builtin_amdgcn_perm(hi, lo, 0x07060302u);  // {hi.b3,hi.b2,lo.b3,lo.b2}
      }
      // half-wave exchange -> A-layout (lane m=q holds P[q][k=8*l5+j])
      uint32_t s1a = l5 ? o[0] : o[2], s1b = l5 ? o[1] : o[3];
      uint32_t r1a = (uint32_t)__shfl_xor((int)s1a, 32, 64);
      uint32_t r1b = (uint32_t)__shfl_xor((int)s1b, 32, 64);
      uint32_t s2a = l5 ? o[4] : o[6], s2b = l5 ? o[5] : o[7];
      uint32_t r2a = (uint32_t)__shfl_xor((int)s2a, 32, 64);
      uint32_t r2b = (uint32_t)__shfl_xor((int)s2b, 32, 64);
      union { uint32_t u[4]; bf16x8 v; } A1, A2;
      A1.u[0] = l5 ? r1a : o[0];  A1.u[1] = l5 ? r1b : o[1];
      A1.u[2] = l5 ? o[2] : r1a;  A1.u[3] = l5 ? o[3] : r1b;
      A2.u[0] = l5 ? r2a : o[4];  A2.u[1] = l5 ? r2b : o[5];
      A2.u[2] = l5 ? o[6] : r2a;  A2.u[3] = l5 ? o[7] : r2b;
      bf16x8 bv1, bv2;
      #pragma unroll
      for (int i = 0; i < 8; ++i) { bv1[i] = 0; bv2[i] = 0; }
      if (lm < 16) {
        const uint16_t* vp = VTb + (size_t)lm*NN + n0 + l5*8;
        bv1 = *(const bf16x8*)(vp);
        bv2 = *(const bf16x8*)(vp + 16);
      }
      O = __builtin_amdgcn_mfma_f32_32x32x16_bf16(A1.v, bv1, O, 0, 0, 0);
      O = __builtin_amdgcn_mfma_f32_32x32x16_bf16(A2.v, bv2, O, 0, 0, 0);
    }
  }
}

// DUAL: masked stream (K1,VT1,mask) + unmasked stream (K2,VT2), summed.
// !DUAL: single unmasked stream. heads out: [row=b*NN+q][h*16+v] bf16.
template<bool DUAL>
__global__ __launch_bounds__(256) void attn_kernel(
    const uint16_t* __restrict__ Q,
    const uint16_t* __restrict__ K1, const uint16_t* __restrict__ VT1,
    const uint16_t* __restrict__ K2, const uint16_t* __restrict__ VT2,
    const uint32_t* __restrict__ packN, uint16_t* __restrict__ outp)
{
  __shared__ uint4 kpl[DUAL ? 2 : 1][2048];    // 32 KB per plane
  const int hb = blockIdx.y;
  const int h = hb >> 3, b = hb & 7;
  const size_t base = ((size_t)h*NF + (size_t)b*NN)*NK;

  const uint4* k1 = (const uint4*)(K1 + base);
  const uint4* k2 = (const uint4*)(K2 + base);
  for (int i = threadIdx.x; i < 2048; i += 256) {
    int pl = (i & 1)*1024 + (i >> 1);
    kpl[0][pl] = k1[i];
    if (DUAL) kpl[DUAL?1:0][pl] = k2[i];
  }
  __syncthreads();

  const int wave = threadIdx.x >> 6, lane = threadIdx.x & 63;
  const int l5 = lane >> 5, lm = lane & 31;
  const int q0 = blockIdx.x*128 + wave*32;

  const bf16x8 aq = *(const bf16x8*)(Q + base + (size_t)(q0 + lm)*NK + l5*8);
  const uint4* pmw4 = DUAL ? (const uint4*)(packN + ((size_t)b*NN + q0 + lm)*32)
                           : nullptr;

  f32x16 O1, O2;
  #pragma unroll
  for (int i = 0; i < 16; ++i) { O1[i] = 0.f; O2[i] = 0.f; }
  float L1 = 0.f, L2 = 0.f;

  attn_stream<DUAL>(kpl[0], aq, VT1 + (size_t)hb*(NK*NN), pmw4, l5, lm, O1, L1);
  if (DUAL)
    attn_stream<false>(kpl[DUAL?1:0], aq, VT2 + (size_t)hb*(NK*NN), nullptr, l5, lm, O2, L2);

  L1 += __shfl_xor(L1, 32, 64);
  if (DUAL) L2 += __shfl_xor(L2, 32, 64);
  const float i1 = (L1 > 0.f) ? 1.f/L1 : 0.f;
  const float i2 = (DUAL && L2 > 0.f) ? 1.f/L2 : 0.f;

  __syncthreads();                     // all kpl reads done; reuse as L buffer
  float2* Lw = (float2*)&kpl[0][0];
  if (lane < 32) Lw[wave*32 + lm] = make_float2(i1, i2);

  uint16_t* op = outp + ((size_t)b*NN + q0)*128 + h*16;
  if (lm < 16) {
    #pragma unroll
    for (int i = 0; i < 16; ++i) {
      const int r = (i&3) + 8*(i>>2) + 4*l5;
      float2 w = Lw[wave*32 + r];
      float v = O1[i]*w.x + (DUAL ? O2[i]*w.y : 0.f);
      op[(size_t)r*128 + lm] = f2bf(v);
    }
  }
}

// MFMA out-projection: out[row][e] = sum_c heads[row][c] * Wout[c][e]; fp32 out
__global__ __launch_bounds__(256) void outproj_kernel(
    const uint16_t* __restrict__ hn, const uint16_t* __restrict__ hc,
    const float* __restrict__ wn, const float* __restrict__ wc,
    float* __restrict__ out)
{
  __shared__ __align__(16) uint16_t WT[128*LSTR];  // [e][c]
  const int s = blockIdx.y;            // 0 node, 1 color
  const int rb = blockIdx.x;
  const int tid = threadIdx.x;
  const float* wsrc = s ? wc : wn;     // [c=h*16+v][e] row-major 128x128
  #pragma unroll 4
  for (int i = 0; i < 64; ++i) {
    int e = i*256 + tid;
    int c = e >> 7, col = e & 127;
    WT[col*LSTR + c] = f2bf(wsrc[e]);
  }
  __syncthreads();

  const int wave = tid >> 6, lane = tid & 63;
  const int l5 = lane >> 5, lm = lane & 31;
  const int r0 = rb*128 + wave*32;
  const uint16_t* hp = (s ? hc : hn) + (size_t)(r0 + lm)*128 + l5*8;
  bf16x8 afr[8];
  #pragma unroll
  for (int kt = 0; kt < 8; ++kt) afr[kt] = *(const bf16x8*)(hp + kt*16);

  float* dst = out + (size_t)s*((size_t)NF*ND) + (size_t)r0*ND;
  #pragma unroll
  for (int nt = 0; nt < 4; ++nt) {
    f32x16 acc;
    #pragma unroll
    for (int i = 0; i < 16; ++i) acc[i] = 0.f;
    #pragma unroll
    for (int kt = 0; kt < 8; ++kt) {
      bf16x8 b = *(const bf16x8*)(&WT[(nt*32 + lm)*LSTR + kt*16 + l5*8]);
      acc = __builtin_amdgcn_mfma_f32_32x32x16_bf16(afr[kt], b, acc, 0, 0, 0);
    }
    #pragma unroll
    for (int i = 0; i < 16; ++i) {
      int r = (i&3) + 8*(i>>2) + 4*l5;
      dst[(size_t)r*ND + nt*32 + lm] = acc[i];
    }
  }
}

extern "C" void kernel_launch(void* const* d_in, const int* in_sizes, int n_in,
                              void* d_out, int out_size, void* d_ws, size_t ws_size,
                              hipStream_t stream)
{
  const float* q_n = (const float*)d_in[0];
  const float* q_c = (const float*)d_in[1];
  const int* mask = (const int*)d_in[2];
  const float* W[10];
  for (int i = 0; i < 10; ++i) W[i] = (const float*)d_in[3+i];
  // W[0]=W_query_n W[1]=W_key_nn W[2]=W_val_nn W[3]=W_key_c W[4]=W_val_c
  // W[5]=W_query_c W[6]=W_key_n  W[7]=W_val_n  W[8]=W_out_node W[9]=W_out_color

  uint16_t* ws16 = (uint16_t*)d_ws;
  const size_t PE = (size_t)NH*NF*NK;   // 1,048,576 elements per slot
  uint16_t* Qc   = ws16 + 0*PE;
  uint16_t* Kn   = ws16 + 1*PE;
  uint16_t* VTn  = ws16 + 2*PE;   // transposed [hb][16][1024]
  uint16_t* Qn   = ws16 + 3*PE;
  uint16_t* Knn  = ws16 + 4*PE;
  uint16_t* VTnn = ws16 + 5*PE;
  uint16_t* Knc  = ws16 + 6*PE;
  uint16_t* VTnc = ws16 + 7*PE;
  uint16_t* heads_node = ws16 + 8*PE;   // [row][h*16+v] bf16
  // slot 9 dual-use: packN (1 MB) consumed by node attn, then heads_c
  uint32_t* packN   = (uint32_t*)(ws16 + 9*PE);
  uint16_t* heads_c = ws16 + 9*PE;

  pack_kernel<<<2048, 256, 0, stream>>>(mask, packN);

  ProjArgs pa;
  pa.x[0]=q_c; pa.w[0]=W[5];  // Q_c
  pa.x[1]=q_n; pa.w[1]=W[6];  // K_n
  pa.x[2]=q_n; pa.w[2]=W[7];  // V_n  (transposed)
  pa.x[3]=q_n; pa.w[3]=W[0];  // Q_n
  pa.x[4]=q_n; pa.w[4]=W[1];  // K_nn
  pa.x[5]=q_n; pa.w[5]=W[2];  // V_nn (transposed)
  pa.x[6]=q_c; pa.w[6]=W[3];  // K_nc
  pa.x[7]=q_c; pa.w[7]=W[4];  // V_nc (transposed)
  proj_kernel<<<dim3(64, 8), 256, 0, stream>>>(pa, ws16);

  // node: masked nn + unmasked nc fused (consumes packN)
  attn_kernel<true ><<<dim3(8,64), 256, 0, stream>>>(Qn, Knn, VTnn, Knc, VTnc,
                                                     packN, heads_node);
  // color: single stream (output overwrites packN slot, no longer needed)
  attn_kernel<false><<<dim3(8,64), 256, 0, stream>>>(Qc, Kn, VTn, Kn, VTn,
                                                     nullptr, heads_c);

  outproj_kernel<<<dim3(64, 2), 256, 0, stream>>>(heads_node, heads_c, W[8], W[9],
                                                  (float*)d_out);
}

// Round 7
// 179.750 us; speedup vs baseline: 12.7590x; 1.1521x over previous
//
#include <hip/hip_runtime.h>
#include <stdint.h>

#define NH 8
#define NB 8
#define NN 1024
#define ND 128
#define NK 16
#define NF (NB*NN)          // 8192 flat (b,n) rows
#define C2EXP 0.36067376022224085f   // (1/sqrt(16)) * log2(e), folded into Q proj
#define LSTR 136            // LDS row stride (bf16 elems): 272 B = 17*16 B

typedef float f32x16 __attribute__((ext_vector_type(16)));
typedef short bf16x8 __attribute__((ext_vector_type(8)));

__device__ __forceinline__ float bf2f(uint16_t u){ return __uint_as_float(((uint32_t)u)<<16); }
__device__ __forceinline__ uint16_t f2bf(float f){
  uint32_t x = __float_as_uint(f);
  uint32_t r = (x + 0x7fffu + ((x>>16)&1u)) >> 16;   // RNE
  return (uint16_t)r;
}
__device__ __forceinline__ float fast_exp2(float x){
#if __has_builtin(__builtin_amdgcn_exp2f)
  return __builtin_amdgcn_exp2f(x);
#else
  return exp2f(x);
#endif
}

// pack mask n-major: packN[row=b*NN+q][t] bit j = mask[b][q][t*32+j]
__global__ __launch_bounds__(256) void pack_kernel(const int* __restrict__ mask,
                                                   uint32_t* __restrict__ packN){
  const int w = threadIdx.x >> 6, lane = threadIdx.x & 63;
  const int row = blockIdx.x*4 + w;          // 0..8191
  const int* mp = mask + (size_t)row*NN;
  uint32_t* dst = packN + (size_t)row*32;
  for (int wq = 0; wq < 16; ++wq) {
    int v = mp[wq*64 + lane];
    unsigned long long bal = __ballot(v != 0);
    if (lane == 0) { dst[wq*2] = (uint32_t)bal; dst[wq*2+1] = (uint32_t)(bal>>32); }
  }
}

struct ProjArgs { const float* x[8]; const float* w[8]; };

// MFMA projection: block = 128 rows x one projection p (128 out cols).
// fp32 x,W in; bf16 out. Q/K -> [h][row][k]; V (p=2,5,7) -> VT [hb][k][n].
// Q projections (p=0,3) pre-scaled by C2EXP so attention exp is raw exp2.
__global__ __launch_bounds__(256) void proj_kernel(ProjArgs args, uint16_t* ws){
  __shared__ __align__(16) uint16_t WT[128*LSTR];  // [n=h*16+k][d]
  __shared__ __align__(16) uint16_t S[128*LSTR];   // epilogue staging
  const int p = blockIdx.y;
  const int rb = blockIdx.x;           // row-block of 128
  const int tid = threadIdx.x;

  const float* wsrc = args.w[p];       // [h][d][k]
  #pragma unroll 4
  for (int i = 0; i < 64; ++i) {
    int e = i*256 + tid;               // coalesced
    int h = e >> 11, d = (e >> 4) & 127, k = e & 15;
    WT[(h*16 + k)*LSTR + d] = f2bf(wsrc[e]);
  }
  __syncthreads();

  const int wave = tid >> 6, lane = tid & 63;
  const int l5 = lane >> 5, lm = lane & 31;
  const int r0 = rb*128 + wave*32;
  const float* xrow = args.x[p] + (size_t)(r0 + lm)*ND + l5*8;

  bf16x8 afr[8];
  #pragma unroll
  for (int kt = 0; kt < 8; ++kt) {
    float4 f0 = *(const float4*)(xrow + kt*16);
    float4 f1 = *(const float4*)(xrow + kt*16 + 4);
    bf16x8 a;
    a[0]=f2bf(f0.x); a[1]=f2bf(f0.y); a[2]=f2bf(f0.z); a[3]=f2bf(f0.w);
    a[4]=f2bf(f1.x); a[5]=f2bf(f1.y); a[6]=f2bf(f1.z); a[7]=f2bf(f1.w);
    afr[kt] = a;
  }

  const bool tr = (p==2)|(p==5)|(p==7);
  const float qsc = (p==0 || p==3) ? C2EXP : 1.0f;
  #pragma unroll
  for (int nt = 0; nt < 4; ++nt) {
    f32x16 acc;
    #pragma unroll
    for (int i = 0; i < 16; ++i) acc[i] = 0.f;
    #pragma unroll
    for (int kt = 0; kt < 8; ++kt) {
      bf16x8 b = *(const bf16x8*)(&WT[(nt*32 + lm)*LSTR + kt*16 + l5*8]);
      acc = __builtin_amdgcn_mfma_f32_32x32x16_bf16(afr[kt], b, acc, 0, 0, 0);
    }
    #pragma unroll
    for (int i = 0; i < 16; ++i) {
      int r = wave*32 + (i&3) + 8*(i>>2) + 4*l5;   // local row 0..127
      int c = nt*32 + lm;
      if (tr) S[c*LSTR + r] = f2bf(acc[i]*qsc);
      else    S[r*LSTR + c] = f2bf(acc[i]*qsc);
    }
  }
  __syncthreads();

  uint16_t* dst = ws + (size_t)p*((size_t)NH*NF*NK);
  if (!tr) {
    #pragma unroll
    for (int it = 0; it < 8; ++it) {
      int c = it*256 + tid;            // 2048 chunks of 8 elems
      int row = c >> 4, cg = c & 15;
      bf16x8 v = *(const bf16x8*)(&S[row*LSTR + cg*8]);
      int h = cg >> 1, k8 = cg & 1;
      *(bf16x8*)(dst + ((size_t)h*NF + rb*128 + row)*NK + k8*8) = v;
    }
  } else {
    const int b = rb >> 3, nb = (rb & 7)*128;
    #pragma unroll
    for (int it = 0; it < 8; ++it) {
      int c = it*256 + tid;
      int col = c >> 4, ng = c & 15;   // col = h*16+k
      bf16x8 v = *(const bf16x8*)(&S[col*LSTR + ng*8]);
      int h = col >> 4, k = col & 15;
      *(bf16x8*)(dst + ((size_t)(h*NB + b)*NK + k)*NN + nb + ng*8) = v;
    }
  }
}

// One attention stream over this wave's 16 n-tiles (n-half nh).
// S^T form: lane = query col. No max subtraction (scores bounded; softmax
// shift-invariant). O accumulated transposed (O^T = V^T frag (A) x P^T (B)):
// lane holds col q, rows v -> L stays per-lane.
template<bool MASKED>
__device__ __forceinline__ void attn_stream(
    const uint4* __restrict__ kbuf, bf16x8 aq,
    const uint16_t* __restrict__ VTb, const uint4* __restrict__ pmw4,
    int nh, int l5, int lm, f32x16& O, float& L)
{
  f32x16 Z;
  #pragma unroll
  for (int i = 0; i < 16; ++i) Z[i] = 0.f;
  for (int t4 = 0; t4 < 4; ++t4) {
    uint4 mq;
    if (MASKED) mq = pmw4[nh*4 + t4];
    #pragma unroll
    for (int j = 0; j < 4; ++j) {
      const int n0 = (nh*16 + t4*4 + j)*32;
      bf16x8 bk = *(const bf16x8*)(&kbuf[l5*1024 + n0 + lm]);
      // S^T tile: A=K rows, B=Q^T -> lane holds col q=lm, rows n
      f32x16 St = __builtin_amdgcn_mfma_f32_32x32x16_bf16(bk, aq, Z, 0, 0, 0);
      uint32_t mws = 0;
      if (MASKED) {
        uint32_t mw = (j==0) ? mq.x : (j==1) ? mq.y : (j==2) ? mq.z : mq.w;
        mws = mw >> (4*l5);
      }
      float p[16];
      #pragma unroll
      for (int i = 0; i < 16; ++i) {
        float pv = fast_exp2(St[i]);           // Q pre-scaled by C2EXP
        if (MASKED && ((mws >> ((i&3) + 8*(i>>2))) & 1u)) pv = 0.f;
        L += pv;
        p[i] = pv;
      }
      // truncate-pack p pairs (rows 2k,2k+1 of col q) into bf16 dwords
      uint32_t o[8];
      #pragma unroll
      for (int k = 0; k < 8; ++k)
        o[k] = __builtin_amdgcn_perm(__float_as_uint(p[2*k+1]),
                                     __float_as_uint(p[2*k]), 0x07060302u);
      // assemble P^T B-frags via half-wave exchange
      uint32_t s1 = l5 ? o[0] : o[2], s2 = l5 ? o[1] : o[3];
      uint32_t r1 = (uint32_t)__shfl_xor((int)s1, 32, 64);
      uint32_t r2 = (uint32_t)__shfl_xor((int)s2, 32, 64);
      uint32_t s3 = l5 ? o[4] : o[6], s4 = l5 ? o[5] : o[7];
      uint32_t r3 = (uint32_t)__shfl_xor((int)s3, 32, 64);
      uint32_t r4 = (uint32_t)__shfl_xor((int)s4, 32, 64);
      union { uint32_t u[4]; bf16x8 v; } B1, B2;
      B1.u[0] = l5 ? r1 : o[0];  B1.u[1] = l5 ? r2 : o[1];
      B1.u[2] = l5 ? o[2] : r1;  B1.u[3] = l5 ? o[3] : r2;
      B2.u[0] = l5 ? r3 : o[4];  B2.u[1] = l5 ? r4 : o[5];
      B2.u[2] = l5 ? o[6] : r3;  B2.u[3] = l5 ? o[7] : r4;
      bf16x8 av1, av2;
      #pragma unroll
      for (int i = 0; i < 8; ++i) { av1[i] = 0; av2[i] = 0; }
      if (lm < 16) {
        const uint16_t* vp = VTb + (size_t)lm*NN + n0 + l5*8;
        av1 = *(const bf16x8*)(vp);
        av2 = *(const bf16x8*)(vp + 16);
      }
      O = __builtin_amdgcn_mfma_f32_32x32x16_bf16(av1, B1.v, O, 0, 0, 0);
      O = __builtin_amdgcn_mfma_f32_32x32x16_bf16(av2, B2.v, O, 0, 0, 0);
    }
  }
}

// 512 threads = 8 waves: wave = qt(4) x nh(2). Each block: 128 q-rows of one
// (h,b). K staged per stream (32 KB); partials combined cross-nh via LDS.
// heads out: [row=b*NN+q][h*16+v] bf16.
template<bool DUAL>
__global__ __launch_bounds__(512, 4) void attn_kernel(
    const uint16_t* __restrict__ Q,
    const uint16_t* __restrict__ K1, const uint16_t* __restrict__ VT1,
    const uint16_t* __restrict__ K2, const uint16_t* __restrict__ VT2,
    const uint32_t* __restrict__ packN, uint16_t* __restrict__ outp)
{
  __shared__ uint4 kbuf[2048];               // 32 KB, plane-split
  __shared__ float comb[4*2*32*18];          // 18 KB partial exchange
  const int hb = blockIdx.y;
  const int h = hb >> 3, b = hb & 7;
  const size_t base = ((size_t)h*NF + (size_t)b*NN)*NK;
  const int tid = threadIdx.x;

  const uint4* k1 = (const uint4*)(K1 + base);
  for (int i = tid; i < 2048; i += 512)
    kbuf[(i & 1)*1024 + (i >> 1)] = k1[i];
  __syncthreads();

  const int wave = tid >> 6, lane = tid & 63;
  const int l5 = lane >> 5, lm = lane & 31;
  const int qt = wave & 3, nh = wave >> 2;
  const int q = blockIdx.x*128 + qt*32 + lm;

  const bf16x8 aq = *(const bf16x8*)(Q + base + (size_t)q*NK + l5*8);
  const uint4* pmw4 = DUAL ? (const uint4*)(packN + ((size_t)b*NN + q)*32)
                           : nullptr;

  f32x16 O1, O2;
  #pragma unroll
  for (int i = 0; i < 16; ++i) { O1[i] = 0.f; O2[i] = 0.f; }
  float L1 = 0.f, L2 = 0.f;

  attn_stream<DUAL>(kbuf, aq, VT1 + (size_t)hb*(NK*NN), pmw4, nh, l5, lm, O1, L1);
  if (DUAL) {
    __syncthreads();
    const uint4* k2 = (const uint4*)(K2 + base);
    for (int i = tid; i < 2048; i += 512)
      kbuf[(i & 1)*1024 + (i >> 1)] = k2[i];
    __syncthreads();
    attn_stream<false>(kbuf, aq, VT2 + (size_t)hb*(NK*NN), nullptr, nh, l5, lm, O2, L2);
  }

  L1 += __shfl_xor(L1, 32, 64);
  if (DUAL) L2 += __shfl_xor(L2, 32, 64);

  float* cw = comb + ((size_t)(qt*2 + l5)*32 + lm)*18;
  __syncthreads();
  if (nh == 1) {
    #pragma unroll
    for (int i = 0; i < 8; ++i) cw[i] = O1[i];
    if (DUAL) {
      #pragma unroll
      for (int i = 0; i < 8; ++i) cw[8+i] = O2[i];
    }
    cw[16] = L1; cw[17] = L2;
  }
  __syncthreads();
  if (nh == 0) {
    const float l1 = L1 + cw[16];
    const float i1 = (l1 > 0.f) ? 1.f/l1 : 0.f;
    float i2 = 0.f;
    if (DUAL) { const float l2 = L2 + cw[17]; i2 = (l2 > 0.f) ? 1.f/l2 : 0.f; }
    // lane(l5) holds v rows {l5*4..l5*4+3, 8+l5*4..11+l5*4} for col q
    uint32_t w[4];
    #pragma unroll
    for (int k = 0; k < 4; ++k) {
      float va = (O1[2*k]   + cw[2*k])  *i1;
      float vb = (O1[2*k+1] + cw[2*k+1])*i1;
      if (DUAL) { va += (O2[2*k] + cw[8+2*k])*i2; vb += (O2[2*k+1] + cw[8+2*k+1])*i2; }
      w[k] = ((uint32_t)f2bf(vb) << 16) | f2bf(va);
    }
    uint16_t* hp = outp + ((size_t)b*NN + q)*128 + h*16 + l5*4;
    *(uint2*)(hp)     = make_uint2(w[0], w[1]);   // v = l5*4 .. +3
    *(uint2*)(hp + 8) = make_uint2(w[2], w[3]);   // v = 8+l5*4 .. +3
  }
}

// MFMA out-projection: out[row][e] = sum_c heads[row][c] * Wout[c][e]; fp32 out
__global__ __launch_bounds__(256) void outproj_kernel(
    const uint16_t* __restrict__ hn, const uint16_t* __restrict__ hc,
    const float* __restrict__ wn, const float* __restrict__ wc,
    float* __restrict__ out)
{
  __shared__ __align__(16) uint16_t WT[128*LSTR];  // [e][c]
  const int s = blockIdx.y;            // 0 node, 1 color
  const int rb = blockIdx.x;
  const int tid = threadIdx.x;
  const float* wsrc = s ? wc : wn;     // [c=h*16+v][e] row-major 128x128
  #pragma unroll 4
  for (int i = 0; i < 64; ++i) {
    int e = i*256 + tid;
    int c = e >> 7, col = e & 127;
    WT[col*LSTR + c] = f2bf(wsrc[e]);
  }
  __syncthreads();

  const int wave = tid >> 6, lane = tid & 63;
  const int l5 = lane >> 5, lm = lane & 31;
  const int r0 = rb*128 + wave*32;
  const uint16_t* hp = (s ? hc : hn) + (size_t)(r0 + lm)*128 + l5*8;
  bf16x8 afr[8];
  #pragma unroll
  for (int kt = 0; kt < 8; ++kt) afr[kt] = *(const bf16x8*)(hp + kt*16);

  float* dst = out + (size_t)s*((size_t)NF*ND) + (size_t)r0*ND;
  #pragma unroll
  for (int nt = 0; nt < 4; ++nt) {
    f32x16 acc;
    #pragma unroll
    for (int i = 0; i < 16; ++i) acc[i] = 0.f;
    #pragma unroll
    for (int kt = 0; kt < 8; ++kt) {
      bf16x8 b = *(const bf16x8*)(&WT[(nt*32 + lm)*LSTR + kt*16 + l5*8]);
      acc = __builtin_amdgcn_mfma_f32_32x32x16_bf16(afr[kt], b, acc, 0, 0, 0);
    }
    #pragma unroll
    for (int i = 0; i < 16; ++i) {
      int r = (i&3) + 8*(i>>2) + 4*l5;
      dst[(size_t)r*ND + nt*32 + lm] = acc[i];
    }
  }
}

extern "C" void kernel_launch(void* const* d_in, const int* in_sizes, int n_in,
                              void* d_out, int out_size, void* d_ws, size_t ws_size,
                              hipStream_t stream)
{
  const float* q_n = (const float*)d_in[0];
  const float* q_c = (const float*)d_in[1];
  const int* mask = (const int*)d_in[2];
  const float* W[10];
  for (int i = 0; i < 10; ++i) W[i] = (const float*)d_in[3+i];
  // W[0]=W_query_n W[1]=W_key_nn W[2]=W_val_nn W[3]=W_key_c W[4]=W_val_c
  // W[5]=W_query_c W[6]=W_key_n  W[7]=W_val_n  W[8]=W_out_node W[9]=W_out_color

  uint16_t* ws16 = (uint16_t*)d_ws;
  const size_t PE = (size_t)NH*NF*NK;   // 1,048,576 elements per slot
  uint16_t* Qc   = ws16 + 0*PE;
  uint16_t* Kn   = ws16 + 1*PE;
  uint16_t* VTn  = ws16 + 2*PE;   // transposed [hb][16][1024]
  uint16_t* Qn   = ws16 + 3*PE;
  uint16_t* Knn  = ws16 + 4*PE;
  uint16_t* VTnn = ws16 + 5*PE;
  uint16_t* Knc  = ws16 + 6*PE;
  uint16_t* VTnc = ws16 + 7*PE;
  uint16_t* heads_node = ws16 + 8*PE;   // [row][h*16+v] bf16
  // slot 9 dual-use: packN (1 MB) consumed by node attn, then heads_c
  uint32_t* packN   = (uint32_t*)(ws16 + 9*PE);
  uint16_t* heads_c = ws16 + 9*PE;

  pack_kernel<<<2048, 256, 0, stream>>>(mask, packN);

  ProjArgs pa;
  pa.x[0]=q_c; pa.w[0]=W[5];  // Q_c (pre-scaled C2EXP)
  pa.x[1]=q_n; pa.w[1]=W[6];  // K_n
  pa.x[2]=q_n; pa.w[2]=W[7];  // V_n  (transposed)
  pa.x[3]=q_n; pa.w[3]=W[0];  // Q_n (pre-scaled C2EXP)
  pa.x[4]=q_n; pa.w[4]=W[1];  // K_nn
  pa.x[5]=q_n; pa.w[5]=W[2];  // V_nn (transposed)
  pa.x[6]=q_c; pa.w[6]=W[3];  // K_nc
  pa.x[7]=q_c; pa.w[7]=W[4];  // V_nc (transposed)
  proj_kernel<<<dim3(64, 8), 256, 0, stream>>>(pa, ws16);

  // node: masked nn + unmasked nc fused (consumes packN)
  attn_kernel<true ><<<dim3(8,64), 512, 0, stream>>>(Qn, Knn, VTnn, Knc, VTnc,
                                                     packN, heads_node);
  // color: single stream (output overwrites packN slot, no longer needed)
  attn_kernel<false><<<dim3(8,64), 512, 0, stream>>>(Qc, Kn, VTn, Kn, VTn,
                                                     nullptr, heads_c);

  outproj_kernel<<<dim3(64, 2), 256, 0, stream>>>(heads_node, heads_c, W[8], W[9],
                                                  (float*)d_out);
}

// Round 8
// 167.782 us; speedup vs baseline: 13.6691x; 1.0713x over previous
//
#include <hip/hip_runtime.h>
#include <stdint.h>

#define NH 8
#define NB 8
#define NN 1024
#define ND 128
#define NK 16
#define NF (NB*NN)          // 8192 flat (b,n) rows
#define C2EXP 0.36067376022224085f   // (1/sqrt(16)) * log2(e), folded into Q proj
#define LSTR 136            // LDS row stride (bf16 elems): 272 B = 17*16 B

typedef float f32x16 __attribute__((ext_vector_type(16)));
typedef short bf16x8 __attribute__((ext_vector_type(8)));

__device__ __forceinline__ uint16_t f2bf(float f){
  uint32_t x = __float_as_uint(f);
  uint32_t r = (x + 0x7fffu + ((x>>16)&1u)) >> 16;   // RNE
  return (uint16_t)r;
}
__device__ __forceinline__ float fast_exp2(float x){
#if __has_builtin(__builtin_amdgcn_exp2f)
  return __builtin_amdgcn_exp2f(x);
#else
  return exp2f(x);
#endif
}

// pack mask n-major: packN[row=b*NN+q][t] bit j = mask[b][q][t*32+j]
__global__ __launch_bounds__(256) void pack_kernel(const int* __restrict__ mask,
                                                   uint32_t* __restrict__ packN){
  const int w = threadIdx.x >> 6, lane = threadIdx.x & 63;
  const int row = blockIdx.x*4 + w;          // 0..8191
  const int* mp = mask + (size_t)row*NN;
  uint32_t* dst = packN + (size_t)row*32;
  for (int wq = 0; wq < 16; ++wq) {
    int v = mp[wq*64 + lane];
    unsigned long long bal = __ballot(v != 0);
    if (lane == 0) { dst[wq*2] = (uint32_t)bal; dst[wq*2+1] = (uint32_t)(bal>>32); }
  }
}

struct ProjArgs { const float* x[8]; const float* w[8]; };

// MFMA projection: block = 128 rows x one projection p (128 out cols).
// fp32 x,W in; bf16 out. Q/K -> [h][row][k]; V (p=2,5,7) -> VT [hb][k][n'],
// with n' = mu(n): within each 16-group swap quartets 1<->2 (involution).
// mu makes the attention P-pack directly usable as the PV B-fragment.
// Q projections (p=0,3) pre-scaled by C2EXP so attention exp is raw exp2.
__global__ __launch_bounds__(256) void proj_kernel(ProjArgs args, uint16_t* ws){
  __shared__ __align__(16) uint16_t WT[128*LSTR];  // [n=h*16+k][d]
  __shared__ __align__(16) uint16_t S[128*LSTR];   // epilogue staging
  const int p = blockIdx.y;
  const int rb = blockIdx.x;           // row-block of 128
  const int tid = threadIdx.x;

  const float4* w4 = (const float4*)args.w[p];     // [h][d][k] fp32
  #pragma unroll
  for (int i = 0; i < 16; ++i) {
    int e4 = i*256 + tid;              // coalesced float4
    float4 f = w4[e4];
    int e = e4*4;
    int h = e >> 11, d = (e >> 4) & 127, k = e & 15;   // k in {0,4,8,12}
    uint16_t* wr = &WT[(h*16 + k)*LSTR + d];
    wr[0*LSTR] = f2bf(f.x); wr[1*LSTR] = f2bf(f.y);
    wr[2*LSTR] = f2bf(f.z); wr[3*LSTR] = f2bf(f.w);
  }
  __syncthreads();

  const int wave = tid >> 6, lane = tid & 63;
  const int l5 = lane >> 5, lm = lane & 31;
  const int r0 = rb*128 + wave*32;
  const float* xrow = args.x[p] + (size_t)(r0 + lm)*ND + l5*8;

  bf16x8 afr[8];
  #pragma unroll
  for (int kt = 0; kt < 8; ++kt) {
    float4 f0 = *(const float4*)(xrow + kt*16);
    float4 f1 = *(const float4*)(xrow + kt*16 + 4);
    bf16x8 a;
    a[0]=f2bf(f0.x); a[1]=f2bf(f0.y); a[2]=f2bf(f0.z); a[3]=f2bf(f0.w);
    a[4]=f2bf(f1.x); a[5]=f2bf(f1.y); a[6]=f2bf(f1.z); a[7]=f2bf(f1.w);
    afr[kt] = a;
  }

  const bool tr = (p==2)|(p==5)|(p==7);
  const float qsc = (p==0 || p==3) ? C2EXP : 1.0f;
  #pragma unroll
  for (int nt = 0; nt < 4; ++nt) {
    f32x16 acc;
    #pragma unroll
    for (int i = 0; i < 16; ++i) acc[i] = 0.f;
    #pragma unroll
    for (int kt = 0; kt < 8; ++kt) {
      bf16x8 b = *(const bf16x8*)(&WT[(nt*32 + lm)*LSTR + kt*16 + l5*8]);
      acc = __builtin_amdgcn_mfma_f32_32x32x16_bf16(afr[kt], b, acc, 0, 0, 0);
    }
    #pragma unroll
    for (int i = 0; i < 16; ++i) {
      int r = wave*32 + (i&3) + 8*(i>>2) + 4*l5;   // local row 0..127
      int c = nt*32 + lm;
      if (tr) {
        int t2 = (r>>2)&3;                         // mu permutation on n
        int rp = (t2==1 || t2==2) ? (r^12) : r;
        S[c*LSTR + rp] = f2bf(acc[i]);
      } else {
        S[r*LSTR + c] = f2bf(acc[i]*qsc);
      }
    }
  }
  __syncthreads();

  uint16_t* dst = ws + (size_t)p*((size_t)NH*NF*NK);
  if (!tr) {
    #pragma unroll
    for (int it = 0; it < 8; ++it) {
      int c = it*256 + tid;            // 2048 chunks of 8 elems
      int row = c >> 4, cg = c & 15;
      bf16x8 v = *(const bf16x8*)(&S[row*LSTR + cg*8]);
      int h = cg >> 1, k8 = cg & 1;
      *(bf16x8*)(dst + ((size_t)h*NF + rb*128 + row)*NK + k8*8) = v;
    }
  } else {
    const int b = rb >> 3, nb = (rb & 7)*128;
    #pragma unroll
    for (int it = 0; it < 8; ++it) {
      int c = it*256 + tid;
      int col = c >> 4, ng = c & 15;   // col = h*16+k
      bf16x8 v = *(const bf16x8*)(&S[col*LSTR + ng*8]);
      int h = col >> 4, k = col & 15;
      *(bf16x8*)(dst + ((size_t)(h*NB + b)*NK + k)*NN + nb + ng*8) = v;
    }
  }
}

// One attention stream over this wave's 16 n-tiles (n-half nh).
// S^T form: lane = query col. No max subtraction (scores bounded; softmax
// shift-invariant). O^T = V^T(A) x P^T(B); V^T is mu-permuted in n so the
// packed exp dwords ARE the B-fragment (no cross-lane exchange).
// V^T row v=16 is ones -> O[reg 8] accumulates L for free.
template<bool MASKED>
__device__ __forceinline__ void attn_stream(
    const uint4* __restrict__ kbuf, bf16x8 aq,
    const uint16_t* __restrict__ VTb, const uint4* __restrict__ pmw4,
    int nh, int l5, int lm, f32x16& O)
{
  f32x16 Z;
  #pragma unroll
  for (int i = 0; i < 16; ++i) Z[i] = 0.f;
  for (int t4 = 0; t4 < 4; ++t4) {
    uint4 mq;
    if (MASKED) mq = pmw4[nh*4 + t4];
    #pragma unroll
    for (int j = 0; j < 4; ++j) {
      const int n0 = (nh*16 + t4*4 + j)*32;
      bf16x8 bk = *(const bf16x8*)(&kbuf[l5*1024 + n0 + lm]);
      // S^T tile: A=K rows, B=Q^T -> lane holds col q=lm, rows n
      f32x16 St = __builtin_amdgcn_mfma_f32_32x32x16_bf16(bk, aq, Z, 0, 0, 0);
      uint32_t mws = 0;
      if (MASKED) {
        uint32_t mw = (j==0) ? mq.x : (j==1) ? mq.y : (j==2) ? mq.z : mq.w;
        mws = mw >> (4*l5);
      }
      float p[16];
      #pragma unroll
      for (int i = 0; i < 16; ++i) {
        float pv = fast_exp2(St[i]);           // Q pre-scaled by C2EXP
        if (MASKED && ((mws >> ((i&3) + 8*(i>>2))) & 1u)) pv = 0.f;
        p[i] = pv;
      }
      // truncate-pack pairs; via mu-permuted V^T these are B-frags directly
      union { uint32_t u[4]; bf16x8 v; } B1, B2;
      #pragma unroll
      for (int k = 0; k < 4; ++k) {
        B1.u[k] = __builtin_amdgcn_perm(__float_as_uint(p[2*k+1]),
                                        __float_as_uint(p[2*k]),   0x07060302u);
        B2.u[k] = __builtin_amdgcn_perm(__float_as_uint(p[2*k+9]),
                                        __float_as_uint(p[2*k+8]), 0x07060302u);
      }
      bf16x8 av1, av2;
      #pragma unroll
      for (int i = 0; i < 8; ++i) { av1[i] = 0; av2[i] = 0; }
      if (lm < 16) {
        const uint16_t* vp = VTb + (size_t)lm*NN + n0 + l5*8;
        av1 = *(const bf16x8*)(vp);
        av2 = *(const bf16x8*)(vp + 16);
      } else if (lm == 16) {
        #pragma unroll
        for (int i = 0; i < 8; ++i) { av1[i] = (short)0x3F80; av2[i] = (short)0x3F80; }
      }
      O = __builtin_amdgcn_mfma_f32_32x32x16_bf16(av1, B1.v, O, 0, 0, 0);
      O = __builtin_amdgcn_mfma_f32_32x32x16_bf16(av2, B2.v, O, 0, 0, 0);
    }
  }
}

// Fused attention: z=0 -> node (masked nn + nc, summed); z=1 -> color.
// 512 threads = 8 waves: wave = qt(4) x nh(2); block = 128 q-rows of (h,b).
// heads out: [row=b*NN+q][h*16+v] bf16.
__global__ __launch_bounds__(512, 4) void attn_kernel(
    const uint16_t* __restrict__ Qn_, const uint16_t* __restrict__ K1n,
    const uint16_t* __restrict__ V1n, const uint16_t* __restrict__ K2n,
    const uint16_t* __restrict__ V2n,
    const uint16_t* __restrict__ Qc_, const uint16_t* __restrict__ K1c,
    const uint16_t* __restrict__ V1c,
    const uint32_t* __restrict__ packN,
    uint16_t* __restrict__ hn_, uint16_t* __restrict__ hc_)
{
  __shared__ uint4 kbuf[2048];               // 32 KB, plane-split
  __shared__ float comb[4*2*32*18];          // 18 KB partial exchange
  const bool dual = (blockIdx.z == 0);
  const uint16_t* Q   = dual ? Qn_ : Qc_;
  const uint16_t* K1  = dual ? K1n : K1c;
  const uint16_t* VT1 = dual ? V1n : V1c;
  uint16_t* outp      = dual ? hn_ : hc_;

  const int hb = blockIdx.y;
  const int h = hb >> 3, b = hb & 7;
  const size_t base = ((size_t)h*NF + (size_t)b*NN)*NK;
  const int tid = threadIdx.x;

  const uint4* k1 = (const uint4*)(K1 + base);
  for (int i = tid; i < 2048; i += 512)
    kbuf[(i & 1)*1024 + (i >> 1)] = k1[i];
  __syncthreads();

  const int wave = tid >> 6, lane = tid & 63;
  const int l5 = lane >> 5, lm = lane & 31;
  const int qt = wave & 3, nh = wave >> 2;
  const int q = blockIdx.x*128 + qt*32 + lm;

  const bf16x8 aq = *(const bf16x8*)(Q + base + (size_t)q*NK + l5*8);
  const uint4* pmw4 = (const uint4*)(packN + ((size_t)b*NN + q)*32);

  f32x16 O1, O2;
  #pragma unroll
  for (int i = 0; i < 16; ++i) { O1[i] = 0.f; O2[i] = 0.f; }

  if (dual) {
    attn_stream<true>(kbuf, aq, V1n + (size_t)hb*(NK*NN), pmw4, nh, l5, lm, O1);
    __syncthreads();
    const uint4* k2 = (const uint4*)(K2n + base);
    for (int i = tid; i < 2048; i += 512)
      kbuf[(i & 1)*1024 + (i >> 1)] = k2[i];
    __syncthreads();
    attn_stream<false>(kbuf, aq, V2n + (size_t)hb*(NK*NN), nullptr, nh, l5, lm, O2);
  } else {
    attn_stream<false>(kbuf, aq, V1c + (size_t)hb*(NK*NN), nullptr, nh, l5, lm, O1);
  }

  // L = O[reg 8] (row v=16, ones): l5=0 lanes hold it, l5=1 hold 0
  float L1 = O1[8] + __shfl_xor(O1[8], 32, 64);
  float L2 = O2[8] + __shfl_xor(O2[8], 32, 64);

  float* cw = comb + ((size_t)(qt*2 + l5)*32 + lm)*18;
  if (nh == 1) {
    #pragma unroll
    for (int i = 0; i < 8; ++i) cw[i] = O1[i];
    if (dual) {
      #pragma unroll
      for (int i = 0; i < 8; ++i) cw[8+i] = O2[i];
    }
    cw[16] = L1; cw[17] = L2;
  }
  __syncthreads();
  if (nh == 0) {
    const float l1 = L1 + cw[16];
    const float i1 = (l1 > 0.f) ? 1.f/l1 : 0.f;
    float i2 = 0.f;
    if (dual) { const float l2 = L2 + cw[17]; i2 = (l2 > 0.f) ? 1.f/l2 : 0.f; }
    uint32_t w[4];
    #pragma unroll
    for (int k = 0; k < 4; ++k) {
      float va = (O1[2*k]   + cw[2*k])  *i1;
      float vb = (O1[2*k+1] + cw[2*k+1])*i1;
      if (dual) { va += (O2[2*k] + cw[8+2*k])*i2; vb += (O2[2*k+1] + cw[8+2*k+1])*i2; }
      w[k] = ((uint32_t)f2bf(vb) << 16) | f2bf(va);
    }
    uint16_t* hp = outp + ((size_t)b*NN + q)*128 + h*16 + l5*4;
    *(uint2*)(hp)     = make_uint2(w[0], w[1]);   // v = l5*4 .. +3
    *(uint2*)(hp + 8) = make_uint2(w[2], w[3]);   // v = 8+l5*4 .. +3
  }
}

// MFMA out-projection: out[row][e] = sum_c heads[row][c] * Wout[c][e]; fp32 out.
// 64 rows/block; wave = (rowhalf rt, nt-pair nh2).
__global__ __launch_bounds__(256) void outproj_kernel(
    const uint16_t* __restrict__ hn, const uint16_t* __restrict__ hc,
    const float* __restrict__ wn, const float* __restrict__ wc,
    float* __restrict__ out)
{
  __shared__ __align__(16) uint16_t WT[128*LSTR];  // [e][c]
  const int s = blockIdx.y;            // 0 node, 1 color
  const int rb = blockIdx.x;           // 128 blocks of 64 rows
  const int tid = threadIdx.x;
  const float* wsrc = s ? wc : wn;     // [c=h*16+v][e] row-major 128x128
  const float4* w4 = (const float4*)wsrc;
  #pragma unroll
  for (int i = 0; i < 16; ++i) {
    int e4 = i*256 + tid;
    float4 f = w4[e4];
    int e = e4*4;
    int c = e >> 7, col = e & 127;     // 4 consecutive cols, same c
    uint16_t* wr = &WT[col*LSTR + c];
    wr[0*LSTR] = f2bf(f.x); wr[1*LSTR] = f2bf(f.y);
    wr[2*LSTR] = f2bf(f.z); wr[3*LSTR] = f2bf(f.w);
  }
  __syncthreads();

  const int wave = tid >> 6, lane = tid & 63;
  const int l5 = lane >> 5, lm = lane & 31;
  const int rt = wave & 1, nh2 = wave >> 1;
  const int r0 = rb*64 + rt*32;
  const uint16_t* hp = (s ? hc : hn) + (size_t)(r0 + lm)*128 + l5*8;
  bf16x8 afr[8];
  #pragma unroll
  for (int kt = 0; kt < 8; ++kt) afr[kt] = *(const bf16x8*)(hp + kt*16);

  float* dst = out + (size_t)s*((size_t)NF*ND) + (size_t)r0*ND;
  #pragma unroll
  for (int nt2 = 0; nt2 < 2; ++nt2) {
    const int nt = nh2*2 + nt2;
    f32x16 acc;
    #pragma unroll
    for (int i = 0; i < 16; ++i) acc[i] = 0.f;
    #pragma unroll
    for (int kt = 0; kt < 8; ++kt) {
      bf16x8 b = *(const bf16x8*)(&WT[(nt*32 + lm)*LSTR + kt*16 + l5*8]);
      acc = __builtin_amdgcn_mfma_f32_32x32x16_bf16(afr[kt], b, acc, 0, 0, 0);
    }
    #pragma unroll
    for (int i = 0; i < 16; ++i) {
      int r = (i&3) + 8*(i>>2) + 4*l5;
      dst[(size_t)r*ND + nt*32 + lm] = acc[i];
    }
  }
}

extern "C" void kernel_launch(void* const* d_in, const int* in_sizes, int n_in,
                              void* d_out, int out_size, void* d_ws, size_t ws_size,
                              hipStream_t stream)
{
  const float* q_n = (const float*)d_in[0];
  const float* q_c = (const float*)d_in[1];
  const int* mask = (const int*)d_in[2];
  const float* W[10];
  for (int i = 0; i < 10; ++i) W[i] = (const float*)d_in[3+i];
  // W[0]=W_query_n W[1]=W_key_nn W[2]=W_val_nn W[3]=W_key_c W[4]=W_val_c
  // W[5]=W_query_c W[6]=W_key_n  W[7]=W_val_n  W[8]=W_out_node W[9]=W_out_color

  uint16_t* ws16 = (uint16_t*)d_ws;
  const size_t PE = (size_t)NH*NF*NK;   // 1,048,576 elements per slot
  uint16_t* Qc   = ws16 + 0*PE;
  uint16_t* Kn   = ws16 + 1*PE;
  uint16_t* VTn  = ws16 + 2*PE;   // [hb][16][1024], n mu-permuted
  uint16_t* Qn   = ws16 + 3*PE;
  uint16_t* Knn  = ws16 + 4*PE;
  uint16_t* VTnn = ws16 + 5*PE;
  uint16_t* Knc  = ws16 + 6*PE;
  uint16_t* VTnc = ws16 + 7*PE;
  uint16_t* heads_node = ws16 + 8*PE;   // [row][h*16+v] bf16
  // slot 9 dual-use: packN (1 MB) consumed by node attn, then heads_c
  uint32_t* packN   = (uint32_t*)(ws16 + 9*PE);
  uint16_t* heads_c = ws16 + 9*PE;

  pack_kernel<<<2048, 256, 0, stream>>>(mask, packN);

  ProjArgs pa;
  pa.x[0]=q_c; pa.w[0]=W[5];  // Q_c (pre-scaled C2EXP)
  pa.x[1]=q_n; pa.w[1]=W[6];  // K_n
  pa.x[2]=q_n; pa.w[2]=W[7];  // V_n  (transposed, mu-permuted)
  pa.x[3]=q_n; pa.w[3]=W[0];  // Q_n (pre-scaled C2EXP)
  pa.x[4]=q_n; pa.w[4]=W[1];  // K_nn
  pa.x[5]=q_n; pa.w[5]=W[2];  // V_nn (transposed, mu-permuted)
  pa.x[6]=q_c; pa.w[6]=W[3];  // K_nc
  pa.x[7]=q_c; pa.w[7]=W[4];  // V_nc (transposed, mu-permuted)
  proj_kernel<<<dim3(64, 8), 256, 0, stream>>>(pa, ws16);

  // z=0: node (masked nn + nc); z=1: color (overwrites packN slot only via
  // heads_c AFTER node blocks consumed packN? No ordering between z-slices!
  // -> heads_c shares slot 9 with packN; color writes heads_c while node
  //    blocks still read packN. Avoided: color heads go to slot 10.
  attn_kernel<<<dim3(8, 64, 2), 512, 0, stream>>>(
      Qn, Knn, VTnn, Knc, VTnc, Qc, Kn, VTn, packN,
      heads_node, ws16 + 10*PE);

  outproj_kernel<<<dim3(128, 2), 256, 0, stream>>>(heads_node, ws16 + 10*PE,
                                                   W[8], W[9], (float*)d_out);
}

// Round 9
// 167.583 us; speedup vs baseline: 13.6853x; 1.0012x over previous
//
#include <hip/hip_runtime.h>
#include <stdint.h>

#define NH 8
#define NB 8
#define NN 1024
#define ND 128
#define NK 16
#define NF (NB*NN)          // 8192 flat (b,n) rows
#define C2EXP 0.36067376022224085f   // (1/sqrt(16)) * log2(e), folded into Q proj
#define LSTR 136            // LDS row stride (bf16 elems): 272 B = 17*16 B

typedef float f32x16 __attribute__((ext_vector_type(16)));
typedef short bf16x8 __attribute__((ext_vector_type(8)));

__device__ __forceinline__ uint16_t f2bf(float f){
  uint32_t x = __float_as_uint(f);
  uint32_t r = (x + 0x7fffu + ((x>>16)&1u)) >> 16;   // RNE
  return (uint16_t)r;
}
__device__ __forceinline__ float fast_exp2(float x){
#if __has_builtin(__builtin_amdgcn_exp2f)
  return __builtin_amdgcn_exp2f(x);
#else
  return exp2f(x);
#endif
}

// pack mask n-major: packN[row=b*NN+q][t] bit j = mask[b][q][t*32+j]
__global__ __launch_bounds__(256) void pack_kernel(const int* __restrict__ mask,
                                                   uint32_t* __restrict__ packN){
  const int w = threadIdx.x >> 6, lane = threadIdx.x & 63;
  const int row = blockIdx.x*4 + w;          // 0..8191
  const int* mp = mask + (size_t)row*NN;
  uint32_t* dst = packN + (size_t)row*32;
  for (int wq = 0; wq < 16; ++wq) {
    int v = mp[wq*64 + lane];
    unsigned long long bal = __ballot(v != 0);
    if (lane == 0) { dst[wq*2] = (uint32_t)bal; dst[wq*2+1] = (uint32_t)(bal>>32); }
  }
}

struct ProjArgs { const float* x[8]; const float* w[8]; };

// MFMA projection: block = 128 rows x one projection p (128 out cols).
// fp32 x,W in; bf16 out. Q/K -> [h][row][k]; V (p=2,5,7) -> VT [hb][k][n'],
// with n' = mu(n): within each 16-group swap quartets 1<->2 (involution).
// mu makes the attention P-pack directly usable as the PV B-fragment.
// Q projections (p=0,3) pre-scaled by C2EXP so attention exp is raw exp2.
__global__ __launch_bounds__(256) void proj_kernel(ProjArgs args, uint16_t* ws){
  __shared__ __align__(16) uint16_t WT[128*LSTR];  // [n=h*16+k][d]
  __shared__ __align__(16) uint16_t S[128*LSTR];   // epilogue staging
  const int p = blockIdx.y;
  const int rb = blockIdx.x;           // row-block of 128
  const int tid = threadIdx.x;

  const float4* w4 = (const float4*)args.w[p];     // [h][d][k] fp32
  #pragma unroll
  for (int i = 0; i < 16; ++i) {
    int e4 = i*256 + tid;              // coalesced float4
    float4 f = w4[e4];
    int e = e4*4;
    int h = e >> 11, d = (e >> 4) & 127, k = e & 15;   // k in {0,4,8,12}
    uint16_t* wr = &WT[(h*16 + k)*LSTR + d];
    wr[0*LSTR] = f2bf(f.x); wr[1*LSTR] = f2bf(f.y);
    wr[2*LSTR] = f2bf(f.z); wr[3*LSTR] = f2bf(f.w);
  }
  __syncthreads();

  const int wave = tid >> 6, lane = tid & 63;
  const int l5 = lane >> 5, lm = lane & 31;
  const int r0 = rb*128 + wave*32;
  const float* xrow = args.x[p] + (size_t)(r0 + lm)*ND + l5*8;

  bf16x8 afr[8];
  #pragma unroll
  for (int kt = 0; kt < 8; ++kt) {
    float4 f0 = *(const float4*)(xrow + kt*16);
    float4 f1 = *(const float4*)(xrow + kt*16 + 4);
    bf16x8 a;
    a[0]=f2bf(f0.x); a[1]=f2bf(f0.y); a[2]=f2bf(f0.z); a[3]=f2bf(f0.w);
    a[4]=f2bf(f1.x); a[5]=f2bf(f1.y); a[6]=f2bf(f1.z); a[7]=f2bf(f1.w);
    afr[kt] = a;
  }

  const bool tr = (p==2)|(p==5)|(p==7);
  const float qsc = (p==0 || p==3) ? C2EXP : 1.0f;
  #pragma unroll
  for (int nt = 0; nt < 4; ++nt) {
    f32x16 acc;
    #pragma unroll
    for (int i = 0; i < 16; ++i) acc[i] = 0.f;
    #pragma unroll
    for (int kt = 0; kt < 8; ++kt) {
      bf16x8 b = *(const bf16x8*)(&WT[(nt*32 + lm)*LSTR + kt*16 + l5*8]);
      acc = __builtin_amdgcn_mfma_f32_32x32x16_bf16(afr[kt], b, acc, 0, 0, 0);
    }
    #pragma unroll
    for (int i = 0; i < 16; ++i) {
      int r = wave*32 + (i&3) + 8*(i>>2) + 4*l5;   // local row 0..127
      int c = nt*32 + lm;
      if (tr) {
        int t2 = (r>>2)&3;                         // mu permutation on n
        int rp = (t2==1 || t2==2) ? (r^12) : r;
        S[c*LSTR + rp] = f2bf(acc[i]);
      } else {
        S[r*LSTR + c] = f2bf(acc[i]*qsc);
      }
    }
  }
  __syncthreads();

  uint16_t* dst = ws + (size_t)p*((size_t)NH*NF*NK);
  if (!tr) {
    #pragma unroll
    for (int it = 0; it < 8; ++it) {
      int c = it*256 + tid;            // 2048 chunks of 8 elems
      int row = c >> 4, cg = c & 15;
      bf16x8 v = *(const bf16x8*)(&S[row*LSTR + cg*8]);
      int h = cg >> 1, k8 = cg & 1;
      *(bf16x8*)(dst + ((size_t)h*NF + rb*128 + row)*NK + k8*8) = v;
    }
  } else {
    const int b = rb >> 3, nb = (rb & 7)*128;
    #pragma unroll
    for (int it = 0; it < 8; ++it) {
      int c = it*256 + tid;
      int col = c >> 4, ng = c & 15;   // col = h*16+k
      bf16x8 v = *(const bf16x8*)(&S[col*LSTR + ng*8]);
      int h = col >> 4, k = col & 15;
      *(bf16x8*)(dst + ((size_t)(h*NB + b)*NK + k)*NN + nb + ng*8) = v;
    }
  }
}

// One attention stream over this wave's 16 n-tiles (n-half nh).
// S^T form: lane = query col. No max subtraction (scores bounded; softmax
// shift-invariant). O^T = V^T(A) x P^T(B); V^T is mu-permuted in n so the
// packed exp dwords ARE the B-fragment (no cross-lane exchange).
// V^T row v=16 is ones -> O[reg 8] accumulates L for free.
template<bool MASKED>
__device__ __forceinline__ void attn_stream(
    const uint4* __restrict__ kbuf, bf16x8 aq,
    const uint16_t* __restrict__ VTb, const uint4* __restrict__ pmw4,
    int nh, int l5, int lm, f32x16& O)
{
  f32x16 Z;
  #pragma unroll
  for (int i = 0; i < 16; ++i) Z[i] = 0.f;
  for (int t4 = 0; t4 < 4; ++t4) {
    uint4 mq;
    if (MASKED) mq = pmw4[nh*4 + t4];
    #pragma unroll
    for (int j = 0; j < 4; ++j) {
      const int n0 = (nh*16 + t4*4 + j)*32;
      bf16x8 bk = *(const bf16x8*)(&kbuf[l5*1024 + n0 + lm]);
      // S^T tile: A=K rows, B=Q^T -> lane holds col q=lm, rows n
      f32x16 St = __builtin_amdgcn_mfma_f32_32x32x16_bf16(bk, aq, Z, 0, 0, 0);
      uint32_t mws = 0;
      if (MASKED) {
        uint32_t mw = (j==0) ? mq.x : (j==1) ? mq.y : (j==2) ? mq.z : mq.w;
        mws = mw >> (4*l5);
      }
      float p[16];
      #pragma unroll
      for (int i = 0; i < 16; ++i) {
        float pv = fast_exp2(St[i]);           // Q pre-scaled by C2EXP
        if (MASKED && ((mws >> ((i&3) + 8*(i>>2))) & 1u)) pv = 0.f;
        p[i] = pv;
      }
      // truncate-pack pairs; via mu-permuted V^T these are B-frags directly
      union { uint32_t u[4]; bf16x8 v; } B1, B2;
      #pragma unroll
      for (int k = 0; k < 4; ++k) {
        B1.u[k] = __builtin_amdgcn_perm(__float_as_uint(p[2*k+1]),
                                        __float_as_uint(p[2*k]),   0x07060302u);
        B2.u[k] = __builtin_amdgcn_perm(__float_as_uint(p[2*k+9]),
                                        __float_as_uint(p[2*k+8]), 0x07060302u);
      }
      bf16x8 av1, av2;
      #pragma unroll
      for (int i = 0; i < 8; ++i) { av1[i] = 0; av2[i] = 0; }
      if (lm < 16) {
        const uint16_t* vp = VTb + (size_t)lm*NN + n0 + l5*8;
        av1 = *(const bf16x8*)(vp);
        av2 = *(const bf16x8*)(vp + 16);
      } else if (lm == 16) {
        #pragma unroll
        for (int i = 0; i < 8; ++i) { av1[i] = (short)0x3F80; av2[i] = (short)0x3F80; }
      }
      O = __builtin_amdgcn_mfma_f32_32x32x16_bf16(av1, B1.v, O, 0, 0, 0);
      O = __builtin_amdgcn_mfma_f32_32x32x16_bf16(av2, B2.v, O, 0, 0, 0);
    }
  }
}

// Fused attention: z=0 -> node (masked nn + nc, summed); z=1 -> color.
// 512 threads = 8 waves: wave = qt(4) x nh(2); block = 128 q-rows of (h,b).
// LDS: 32 KB kbuf only; the partial-exchange buffer ALIASES kbuf (all kbuf
// reads complete before the combine phase; fenced by __syncthreads) ->
// 4 blocks/CU, grid 1024/256 = exactly 4/CU = full residency.
// heads out: [row=b*NN+q][h*16+v] bf16.
__global__ __launch_bounds__(512, 4) void attn_kernel(
    const uint16_t* __restrict__ Qn_, const uint16_t* __restrict__ K1n,
    const uint16_t* __restrict__ V1n, const uint16_t* __restrict__ K2n,
    const uint16_t* __restrict__ V2n,
    const uint16_t* __restrict__ Qc_, const uint16_t* __restrict__ K1c,
    const uint16_t* __restrict__ V1c,
    const uint32_t* __restrict__ packN,
    uint16_t* __restrict__ hn_, uint16_t* __restrict__ hc_)
{
  __shared__ uint4 kbuf[2048];               // 32 KB, plane-split; aliased below
  const bool dual = (blockIdx.z == 0);
  const uint16_t* Q   = dual ? Qn_ : Qc_;
  const uint16_t* K1  = dual ? K1n : K1c;
  uint16_t* outp      = dual ? hn_ : hc_;

  const int hb = blockIdx.y;
  const int h = hb >> 3, b = hb & 7;
  const size_t base = ((size_t)h*NF + (size_t)b*NN)*NK;
  const int tid = threadIdx.x;

  const uint4* k1 = (const uint4*)(K1 + base);
  for (int i = tid; i < 2048; i += 512)
    kbuf[(i & 1)*1024 + (i >> 1)] = k1[i];
  __syncthreads();

  const int wave = tid >> 6, lane = tid & 63;
  const int l5 = lane >> 5, lm = lane & 31;
  const int qt = wave & 3, nh = wave >> 2;
  const int q = blockIdx.x*128 + qt*32 + lm;

  const bf16x8 aq = *(const bf16x8*)(Q + base + (size_t)q*NK + l5*8);
  const uint4* pmw4 = (const uint4*)(packN + ((size_t)b*NN + q)*32);

  f32x16 O1, O2;
  #pragma unroll
  for (int i = 0; i < 16; ++i) { O1[i] = 0.f; O2[i] = 0.f; }

  if (dual) {
    attn_stream<true>(kbuf, aq, V1n + (size_t)hb*(NK*NN), pmw4, nh, l5, lm, O1);
    __syncthreads();
    const uint4* k2 = (const uint4*)(K2n + base);
    for (int i = tid; i < 2048; i += 512)
      kbuf[(i & 1)*1024 + (i >> 1)] = k2[i];
    __syncthreads();
    attn_stream<false>(kbuf, aq, V2n + (size_t)hb*(NK*NN), nullptr, nh, l5, lm, O2);
  } else {
    attn_stream<false>(kbuf, aq, V1c + (size_t)hb*(NK*NN), nullptr, nh, l5, lm, O1);
  }

  // L = O[reg 8] (row v=16, ones): l5=0 lanes hold it, l5=1 hold 0
  float L1 = O1[8] + __shfl_xor(O1[8], 32, 64);
  float L2 = O2[8] + __shfl_xor(O2[8], 32, 64);

  __syncthreads();                           // all kbuf reads done: safe to alias
  float* cw = ((float*)kbuf) + ((size_t)(qt*2 + l5)*32 + lm)*18;   // 18 KB < 32 KB
  if (nh == 1) {
    #pragma unroll
    for (int i = 0; i < 8; ++i) cw[i] = O1[i];
    if (dual) {
      #pragma unroll
      for (int i = 0; i < 8; ++i) cw[8+i] = O2[i];
    }
    cw[16] = L1; cw[17] = L2;
  }
  __syncthreads();
  if (nh == 0) {
    const float l1 = L1 + cw[16];
    const float i1 = (l1 > 0.f) ? 1.f/l1 : 0.f;
    float i2 = 0.f;
    if (dual) { const float l2 = L2 + cw[17]; i2 = (l2 > 0.f) ? 1.f/l2 : 0.f; }
    uint32_t w[4];
    #pragma unroll
    for (int k = 0; k < 4; ++k) {
      float va = (O1[2*k]   + cw[2*k])  *i1;
      float vb = (O1[2*k+1] + cw[2*k+1])*i1;
      if (dual) { va += (O2[2*k] + cw[8+2*k])*i2; vb += (O2[2*k+1] + cw[8+2*k+1])*i2; }
      w[k] = ((uint32_t)f2bf(vb) << 16) | f2bf(va);
    }
    uint16_t* hp = outp + ((size_t)b*NN + q)*128 + h*16 + l5*4;
    *(uint2*)(hp)     = make_uint2(w[0], w[1]);   // v = l5*4 .. +3
    *(uint2*)(hp + 8) = make_uint2(w[2], w[3]);   // v = 8+l5*4 .. +3
  }
}

// MFMA out-projection: out[row][e] = sum_c heads[row][c] * Wout[c][e]; fp32 out.
// 64 rows/block; wave = (rowhalf rt, nt-pair nh2).
__global__ __launch_bounds__(256) void outproj_kernel(
    const uint16_t* __restrict__ hn, const uint16_t* __restrict__ hc,
    const float* __restrict__ wn, const float* __restrict__ wc,
    float* __restrict__ out)
{
  __shared__ __align__(16) uint16_t WT[128*LSTR];  // [e][c]
  const int s = blockIdx.y;            // 0 node, 1 color
  const int rb = blockIdx.x;           // 128 blocks of 64 rows
  const int tid = threadIdx.x;
  const float* wsrc = s ? wc : wn;     // [c=h*16+v][e] row-major 128x128
  const float4* w4 = (const float4*)wsrc;
  #pragma unroll
  for (int i = 0; i < 16; ++i) {
    int e4 = i*256 + tid;
    float4 f = w4[e4];
    int e = e4*4;
    int c = e >> 7, col = e & 127;     // 4 consecutive cols, same c
    uint16_t* wr = &WT[col*LSTR + c];
    wr[0*LSTR] = f2bf(f.x); wr[1*LSTR] = f2bf(f.y);
    wr[2*LSTR] = f2bf(f.z); wr[3*LSTR] = f2bf(f.w);
  }
  __syncthreads();

  const int wave = tid >> 6, lane = tid & 63;
  const int l5 = lane >> 5, lm = lane & 31;
  const int rt = wave & 1, nh2 = wave >> 1;
  const int r0 = rb*64 + rt*32;
  const uint16_t* hp = (s ? hc : hn) + (size_t)(r0 + lm)*128 + l5*8;
  bf16x8 afr[8];
  #pragma unroll
  for (int kt = 0; kt < 8; ++kt) afr[kt] = *(const bf16x8*)(hp + kt*16);

  float* dst = out + (size_t)s*((size_t)NF*ND) + (size_t)r0*ND;
  #pragma unroll
  for (int nt2 = 0; nt2 < 2; ++nt2) {
    const int nt = nh2*2 + nt2;
    f32x16 acc;
    #pragma unroll
    for (int i = 0; i < 16; ++i) acc[i] = 0.f;
    #pragma unroll
    for (int kt = 0; kt < 8; ++kt) {
      bf16x8 b = *(const bf16x8*)(&WT[(nt*32 + lm)*LSTR + kt*16 + l5*8]);
      acc = __builtin_amdgcn_mfma_f32_32x32x16_bf16(afr[kt], b, acc, 0, 0, 0);
    }
    #pragma unroll
    for (int i = 0; i < 16; ++i) {
      int r = (i&3) + 8*(i>>2) + 4*l5;
      dst[(size_t)r*ND + nt*32 + lm] = acc[i];
    }
  }
}

extern "C" void kernel_launch(void* const* d_in, const int* in_sizes, int n_in,
                              void* d_out, int out_size, void* d_ws, size_t ws_size,
                              hipStream_t stream)
{
  const float* q_n = (const float*)d_in[0];
  const float* q_c = (const float*)d_in[1];
  const int* mask = (const int*)d_in[2];
  const float* W[10];
  for (int i = 0; i < 10; ++i) W[i] = (const float*)d_in[3+i];
  // W[0]=W_query_n W[1]=W_key_nn W[2]=W_val_nn W[3]=W_key_c W[4]=W_val_c
  // W[5]=W_query_c W[6]=W_key_n  W[7]=W_val_n  W[8]=W_out_node W[9]=W_out_color

  uint16_t* ws16 = (uint16_t*)d_ws;
  const size_t PE = (size_t)NH*NF*NK;   // 1,048,576 elements per slot
  uint16_t* Qc   = ws16 + 0*PE;
  uint16_t* Kn   = ws16 + 1*PE;
  uint16_t* VTn  = ws16 + 2*PE;   // [hb][16][1024], n mu-permuted
  uint16_t* Qn   = ws16 + 3*PE;
  uint16_t* Knn  = ws16 + 4*PE;
  uint16_t* VTnn = ws16 + 5*PE;
  uint16_t* Knc  = ws16 + 6*PE;
  uint16_t* VTnc = ws16 + 7*PE;
  uint16_t* heads_node = ws16 + 8*PE;   // [row][h*16+v] bf16
  uint32_t* packN   = (uint32_t*)(ws16 + 9*PE);   // 1 MB
  uint16_t* heads_c = ws16 + 10*PE;     // separate slot: attn z-slices unordered

  pack_kernel<<<2048, 256, 0, stream>>>(mask, packN);

  ProjArgs pa;
  pa.x[0]=q_c; pa.w[0]=W[5];  // Q_c (pre-scaled C2EXP)
  pa.x[1]=q_n; pa.w[1]=W[6];  // K_n
  pa.x[2]=q_n; pa.w[2]=W[7];  // V_n  (transposed, mu-permuted)
  pa.x[3]=q_n; pa.w[3]=W[0];  // Q_n (pre-scaled C2EXP)
  pa.x[4]=q_n; pa.w[4]=W[1];  // K_nn
  pa.x[5]=q_n; pa.w[5]=W[2];  // V_nn (transposed, mu-permuted)
  pa.x[6]=q_c; pa.w[6]=W[3];  // K_nc
  pa.x[7]=q_c; pa.w[7]=W[4];  // V_nc (transposed, mu-permuted)
  proj_kernel<<<dim3(64, 8), 256, 0, stream>>>(pa, ws16);

  attn_kernel<<<dim3(8, 64, 2), 512, 0, stream>>>(
      Qn, Knn, VTnn, Knc, VTnc, Qc, Kn, VTn, packN,
      heads_node, heads_c);

  outproj_kernel<<<dim3(128, 2), 256, 0, stream>>>(heads_node, heads_c,
                                                   W[8], W[9], (float*)d_out);
}

// Round 10
// 165.173 us; speedup vs baseline: 13.8850x; 1.0146x over previous
//
#include <hip/hip_runtime.h>
#include <stdint.h>

#define NH 8
#define NB 8
#define NN 1024
#define ND 128
#define NK 16
#define NF (NB*NN)          // 8192 flat (b,n) rows
#define C2EXP 0.36067376022224085f   // (1/sqrt(16)) * log2(e), folded into Q proj
#define LSTR 136            // LDS row stride (bf16 elems): 272 B = 17*16 B

typedef float f32x16 __attribute__((ext_vector_type(16)));
typedef short bf16x8 __attribute__((ext_vector_type(8)));

__device__ __forceinline__ uint16_t f2bf(float f){
  uint32_t x = __float_as_uint(f);
  uint32_t r = (x + 0x7fffu + ((x>>16)&1u)) >> 16;   // RNE
  return (uint16_t)r;
}
__device__ __forceinline__ float fast_exp2(float x){
#if __has_builtin(__builtin_amdgcn_exp2f)
  return __builtin_amdgcn_exp2f(x);
#else
  return exp2f(x);
#endif
}

// pack mask n-major: packN[row=b*NN+q][t] bit j = mask[b][q][t*32+j].
// Also writes the 1024-elem bf16 ones row used as V^T row 16.
__global__ __launch_bounds__(256) void pack_kernel(const int* __restrict__ mask,
                                                   uint32_t* __restrict__ packN,
                                                   uint16_t* __restrict__ onesw){
  if (blockIdx.x == 0) {
    for (int i = threadIdx.x; i < 1024; i += 256) onesw[i] = 0x3F80;  // 1.0bf
  }
  const int w = threadIdx.x >> 6, lane = threadIdx.x & 63;
  const int row = blockIdx.x*4 + w;          // 0..8191
  const int* mp = mask + (size_t)row*NN;
  uint32_t* dst = packN + (size_t)row*32;
  for (int wq = 0; wq < 16; ++wq) {
    int v = mp[wq*64 + lane];
    unsigned long long bal = __ballot(v != 0);
    if (lane == 0) { dst[wq*2] = (uint32_t)bal; dst[wq*2+1] = (uint32_t)(bal>>32); }
  }
}

struct ProjArgs { const float* x[8]; const float* w[8]; };

// MFMA projection: block = 128 rows x one projection p (128 out cols).
// fp32 x,W in; bf16 out. Q/K -> [h][row][k]; V (p=2,5,7) -> VT [hb][k][n'],
// with n' = mu(n): within each 16-group swap quartets 1<->2 (involution).
// mu makes the attention P-pack directly usable as the PV B-fragment.
// Q projections (p=0,3) pre-scaled by C2EXP so attention exp is raw exp2.
__global__ __launch_bounds__(256) void proj_kernel(ProjArgs args, uint16_t* ws){
  __shared__ __align__(16) uint16_t WT[128*LSTR];  // [n=h*16+k][d]
  __shared__ __align__(16) uint16_t S[128*LSTR];   // epilogue staging
  const int p = blockIdx.y;
  const int rb = blockIdx.x;           // row-block of 128
  const int tid = threadIdx.x;

  const float4* w4 = (const float4*)args.w[p];     // [h][d][k] fp32
  #pragma unroll
  for (int i = 0; i < 16; ++i) {
    int e4 = i*256 + tid;              // coalesced float4
    float4 f = w4[e4];
    int e = e4*4;
    int h = e >> 11, d = (e >> 4) & 127, k = e & 15;   // k in {0,4,8,12}
    uint16_t* wr = &WT[(h*16 + k)*LSTR + d];
    wr[0*LSTR] = f2bf(f.x); wr[1*LSTR] = f2bf(f.y);
    wr[2*LSTR] = f2bf(f.z); wr[3*LSTR] = f2bf(f.w);
  }
  __syncthreads();

  const int wave = tid >> 6, lane = tid & 63;
  const int l5 = lane >> 5, lm = lane & 31;
  const int r0 = rb*128 + wave*32;
  const float* xrow = args.x[p] + (size_t)(r0 + lm)*ND + l5*8;

  bf16x8 afr[8];
  #pragma unroll
  for (int kt = 0; kt < 8; ++kt) {
    float4 f0 = *(const float4*)(xrow + kt*16);
    float4 f1 = *(const float4*)(xrow + kt*16 + 4);
    bf16x8 a;
    a[0]=f2bf(f0.x); a[1]=f2bf(f0.y); a[2]=f2bf(f0.z); a[3]=f2bf(f0.w);
    a[4]=f2bf(f1.x); a[5]=f2bf(f1.y); a[6]=f2bf(f1.z); a[7]=f2bf(f1.w);
    afr[kt] = a;
  }

  const bool tr = (p==2)|(p==5)|(p==7);
  const float qsc = (p==0 || p==3) ? C2EXP : 1.0f;
  #pragma unroll
  for (int nt = 0; nt < 4; ++nt) {
    f32x16 acc;
    #pragma unroll
    for (int i = 0; i < 16; ++i) acc[i] = 0.f;
    #pragma unroll
    for (int kt = 0; kt < 8; ++kt) {
      bf16x8 b = *(const bf16x8*)(&WT[(nt*32 + lm)*LSTR + kt*16 + l5*8]);
      acc = __builtin_amdgcn_mfma_f32_32x32x16_bf16(afr[kt], b, acc, 0, 0, 0);
    }
    #pragma unroll
    for (int i = 0; i < 16; ++i) {
      int r = wave*32 + (i&3) + 8*(i>>2) + 4*l5;   // local row 0..127
      int c = nt*32 + lm;
      if (tr) {
        int t2 = (r>>2)&3;                         // mu permutation on n
        int rp = (t2==1 || t2==2) ? (r^12) : r;
        S[c*LSTR + rp] = f2bf(acc[i]);
      } else {
        S[r*LSTR + c] = f2bf(acc[i]*qsc);
      }
    }
  }
  __syncthreads();

  uint16_t* dst = ws + (size_t)p*((size_t)NH*NF*NK);
  if (!tr) {
    #pragma unroll
    for (int it = 0; it < 8; ++it) {
      int c = it*256 + tid;            // 2048 chunks of 8 elems
      int row = c >> 4, cg = c & 15;
      bf16x8 v = *(const bf16x8*)(&S[row*LSTR + cg*8]);
      int h = cg >> 1, k8 = cg & 1;
      *(bf16x8*)(dst + ((size_t)h*NF + rb*128 + row)*NK + k8*8) = v;
    }
  } else {
    const int b = rb >> 3, nb = (rb & 7)*128;
    #pragma unroll
    for (int it = 0; it < 8; ++it) {
      int c = it*256 + tid;
      int col = c >> 4, ng = c & 15;   // col = h*16+k
      bf16x8 v = *(const bf16x8*)(&S[col*LSTR + ng*8]);
      int h = col >> 4, k = col & 15;
      *(bf16x8*)(dst + ((size_t)(h*NB + b)*NK + k)*NN + nb + ng*8) = v;
    }
  }
}

// One attention stream over this wave's 16 n-tiles (n-half nh).
// S^T form: lane = query col. No max subtraction. O^T = V^T(A) x P^T(B);
// V^T mu-permuted in n so packed exp dwords ARE the B-fragment.
// vbase: per-lane V^T row ptr (lane 16 -> ones row => L in O[reg 8]).
// Depth-1 software pipeline: V loads + QK MFMA for tile t+1 issue before
// the exp/pack/PV of tile t (hides LDS/MFMA/global latency under exp2).
template<bool MASKED>
__device__ __forceinline__ void attn_stream(
    const uint4* __restrict__ kbuf, bf16x8 aq,
    const uint16_t* __restrict__ vbase, const uint4* __restrict__ pmw4,
    int nh, int l5, int lm, f32x16& O)
{
  f32x16 Z;
  #pragma unroll
  for (int i = 0; i < 16; ++i) Z[i] = 0.f;

  uint32_t mw[16];
  if (MASKED) {
    uint4 m0 = pmw4[nh*4+0], m1 = pmw4[nh*4+1];
    uint4 m2 = pmw4[nh*4+2], m3 = pmw4[nh*4+3];
    mw[0]=m0.x; mw[1]=m0.y; mw[2]=m0.z; mw[3]=m0.w;
    mw[4]=m1.x; mw[5]=m1.y; mw[6]=m1.z; mw[7]=m1.w;
    mw[8]=m2.x; mw[9]=m2.y; mw[10]=m2.z; mw[11]=m2.w;
    mw[12]=m3.x; mw[13]=m3.y; mw[14]=m3.z; mw[15]=m3.w;
  }

  const int base_n = nh*512;
  const bool vload = (lm < 17);

  bf16x8 av1, av2, av1n, av2n;
  #pragma unroll
  for (int i = 0; i < 8; ++i) { av1[i]=0; av2[i]=0; av1n[i]=0; av2n[i]=0; }
  if (vload) {
    const uint16_t* vp = vbase + base_n + l5*8;
    av1 = *(const bf16x8*)(vp);
    av2 = *(const bf16x8*)(vp + 16);
  }
  f32x16 Stc = __builtin_amdgcn_mfma_f32_32x32x16_bf16(
      *(const bf16x8*)(&kbuf[l5*1024 + base_n + lm]), aq, Z, 0, 0, 0);

  #pragma unroll
  for (int t = 0; t < 16; ++t) {
    f32x16 Stn;
    if (t < 15) {
      const int n1 = base_n + (t+1)*32;
      if (vload) {
        const uint16_t* vp = vbase + n1 + l5*8;
        av1n = *(const bf16x8*)(vp);
        av2n = *(const bf16x8*)(vp + 16);
      }
      Stn = __builtin_amdgcn_mfma_f32_32x32x16_bf16(
          *(const bf16x8*)(&kbuf[l5*1024 + n1 + lm]), aq, Z, 0, 0, 0);
    }

    const uint32_t mws = MASKED ? (mw[t] >> (4*l5)) : 0u;
    float p[16];
    #pragma unroll
    for (int i = 0; i < 16; ++i) {
      float pv = fast_exp2(Stc[i]);            // Q pre-scaled by C2EXP
      if (MASKED && ((mws >> ((i&3) + 8*(i>>2))) & 1u)) pv = 0.f;
      p[i] = pv;
    }
    // truncate-pack pairs; via mu-permuted V^T these are B-frags directly
    union { uint32_t u[4]; bf16x8 v; } B1, B2;
    #pragma unroll
    for (int k = 0; k < 4; ++k) {
      B1.u[k] = __builtin_amdgcn_perm(__float_as_uint(p[2*k+1]),
                                      __float_as_uint(p[2*k]),   0x07060302u);
      B2.u[k] = __builtin_amdgcn_perm(__float_as_uint(p[2*k+9]),
                                      __float_as_uint(p[2*k+8]), 0x07060302u);
    }
    O = __builtin_amdgcn_mfma_f32_32x32x16_bf16(av1, B1.v, O, 0, 0, 0);
    O = __builtin_amdgcn_mfma_f32_32x32x16_bf16(av2, B2.v, O, 0, 0, 0);

    if (t < 15) { Stc = Stn; av1 = av1n; av2 = av2n; }
  }
}

// Fused attention: z=0 -> node (masked nn + nc, summed); z=1 -> color.
// 512 threads = 8 waves: wave = qt(4) x nh(2); block = 128 q-rows of (h,b).
// LDS: 32 KB kbuf only; combine buffer aliases kbuf (fenced by barriers).
// heads out: [row=b*NN+q][h*16+v] bf16.
__global__ __launch_bounds__(512, 4) void attn_kernel(
    const uint16_t* __restrict__ Qn_, const uint16_t* __restrict__ K1n,
    const uint16_t* __restrict__ V1n, const uint16_t* __restrict__ K2n,
    const uint16_t* __restrict__ V2n,
    const uint16_t* __restrict__ Qc_, const uint16_t* __restrict__ K1c,
    const uint16_t* __restrict__ V1c,
    const uint32_t* __restrict__ packN, const uint16_t* __restrict__ onesb,
    uint16_t* __restrict__ hn_, uint16_t* __restrict__ hc_)
{
  __shared__ uint4 kbuf[2048];               // 32 KB, plane-split; aliased below
  const bool dual = (blockIdx.z == 0);
  const uint16_t* Q   = dual ? Qn_ : Qc_;
  const uint16_t* K1  = dual ? K1n : K1c;
  uint16_t* outp      = dual ? hn_ : hc_;

  const int hb = blockIdx.y;
  const int h = hb >> 3, b = hb & 7;
  const size_t base = ((size_t)h*NF + (size_t)b*NN)*NK;
  const int tid = threadIdx.x;

  const uint4* k1 = (const uint4*)(K1 + base);
  for (int i = tid; i < 2048; i += 512)
    kbuf[(i & 1)*1024 + (i >> 1)] = k1[i];
  __syncthreads();

  const int wave = tid >> 6, lane = tid & 63;
  const int l5 = lane >> 5, lm = lane & 31;
  const int qt = wave & 3, nh = wave >> 2;
  const int q = blockIdx.x*128 + qt*32 + lm;

  const bf16x8 aq = *(const bf16x8*)(Q + base + (size_t)q*NK + l5*8);
  const uint4* pmw4 = (const uint4*)(packN + ((size_t)b*NN + q)*32);

  const uint16_t* VT1 = (dual ? V1n : V1c) + (size_t)hb*(NK*NN);
  const uint16_t* vb1 = (lm < 16) ? (VT1 + (size_t)lm*NN) : onesb;

  f32x16 O1, O2;
  #pragma unroll
  for (int i = 0; i < 16; ++i) { O1[i] = 0.f; O2[i] = 0.f; }

  if (dual) {
    attn_stream<true>(kbuf, aq, vb1, pmw4, nh, l5, lm, O1);
    __syncthreads();
    const uint4* k2 = (const uint4*)(K2n + base);
    for (int i = tid; i < 2048; i += 512)
      kbuf[(i & 1)*1024 + (i >> 1)] = k2[i];
    __syncthreads();
    const uint16_t* VT2 = V2n + (size_t)hb*(NK*NN);
    const uint16_t* vb2 = (lm < 16) ? (VT2 + (size_t)lm*NN) : onesb;
    attn_stream<false>(kbuf, aq, vb2, nullptr, nh, l5, lm, O2);
  } else {
    attn_stream<false>(kbuf, aq, vb1, nullptr, nh, l5, lm, O1);
  }

  // L = O[reg 8] (row v=16, ones): l5=0 lanes hold it, l5=1 hold 0
  float L1 = O1[8] + __shfl_xor(O1[8], 32, 64);
  float L2 = O2[8] + __shfl_xor(O2[8], 32, 64);

  __syncthreads();                           // all kbuf reads done: safe to alias
  float* cw = ((float*)kbuf) + ((size_t)(qt*2 + l5)*32 + lm)*18;   // 18 KB < 32 KB
  if (nh == 1) {
    #pragma unroll
    for (int i = 0; i < 8; ++i) cw[i] = O1[i];
    if (dual) {
      #pragma unroll
      for (int i = 0; i < 8; ++i) cw[8+i] = O2[i];
    }
    cw[16] = L1; cw[17] = L2;
  }
  __syncthreads();
  if (nh == 0) {
    const float l1 = L1 + cw[16];
    const float i1 = (l1 > 0.f) ? 1.f/l1 : 0.f;
    float i2 = 0.f;
    if (dual) { const float l2 = L2 + cw[17]; i2 = (l2 > 0.f) ? 1.f/l2 : 0.f; }
    uint32_t w[4];
    #pragma unroll
    for (int k = 0; k < 4; ++k) {
      float va = (O1[2*k]   + cw[2*k])  *i1;
      float vb = (O1[2*k+1] + cw[2*k+1])*i1;
      if (dual) { va += (O2[2*k] + cw[8+2*k])*i2; vb += (O2[2*k+1] + cw[8+2*k+1])*i2; }
      w[k] = ((uint32_t)f2bf(vb) << 16) | f2bf(va);
    }
    uint16_t* hp = outp + ((size_t)b*NN + q)*128 + h*16 + l5*4;
    *(uint2*)(hp)     = make_uint2(w[0], w[1]);   // v = l5*4 .. +3
    *(uint2*)(hp + 8) = make_uint2(w[2], w[3]);   // v = 8+l5*4 .. +3
  }
}

// MFMA out-projection: out[row][e] = sum_c heads[row][c] * Wout[c][e]; fp32 out.
// 64 rows/block; wave = (rowhalf rt, nt-pair nh2).
__global__ __launch_bounds__(256) void outproj_kernel(
    const uint16_t* __restrict__ hn, const uint16_t* __restrict__ hc,
    const float* __restrict__ wn, const float* __restrict__ wc,
    float* __restrict__ out)
{
  __shared__ __align__(16) uint16_t WT[128*LSTR];  // [e][c]
  const int s = blockIdx.y;            // 0 node, 1 color
  const int rb = blockIdx.x;           // 128 blocks of 64 rows
  const int tid = threadIdx.x;
  const float* wsrc = s ? wc : wn;     // [c=h*16+v][e] row-major 128x128
  const float4* w4 = (const float4*)wsrc;
  #pragma unroll
  for (int i = 0; i < 16; ++i) {
    int e4 = i*256 + tid;
    float4 f = w4[e4];
    int e = e4*4;
    int c = e >> 7, col = e & 127;     // 4 consecutive cols, same c
    uint16_t* wr = &WT[col*LSTR + c];
    wr[0*LSTR] = f2bf(f.x); wr[1*LSTR] = f2bf(f.y);
    wr[2*LSTR] = f2bf(f.z); wr[3*LSTR] = f2bf(f.w);
  }
  __syncthreads();

  const int wave = tid >> 6, lane = tid & 63;
  const int l5 = lane >> 5, lm = lane & 31;
  const int rt = wave & 1, nh2 = wave >> 1;
  const int r0 = rb*64 + rt*32;
  const uint16_t* hp = (s ? hc : hn) + (size_t)(r0 + lm)*128 + l5*8;
  bf16x8 afr[8];
  #pragma unroll
  for (int kt = 0; kt < 8; ++kt) afr[kt] = *(const bf16x8*)(hp + kt*16);

  float* dst = out + (size_t)s*((size_t)NF*ND) + (size_t)r0*ND;
  #pragma unroll
  for (int nt2 = 0; nt2 < 2; ++nt2) {
    const int nt = nh2*2 + nt2;
    f32x16 acc;
    #pragma unroll
    for (int i = 0; i < 16; ++i) acc[i] = 0.f;
    #pragma unroll
    for (int kt = 0; kt < 8; ++kt) {
      bf16x8 b = *(const bf16x8*)(&WT[(nt*32 + lm)*LSTR + kt*16 + l5*8]);
      acc = __builtin_amdgcn_mfma_f32_32x32x16_bf16(afr[kt], b, acc, 0, 0, 0);
    }
    #pragma unroll
    for (int i = 0; i < 16; ++i) {
      int r = (i&3) + 8*(i>>2) + 4*l5;
      dst[(size_t)r*ND + nt*32 + lm] = acc[i];
    }
  }
}

extern "C" void kernel_launch(void* const* d_in, const int* in_sizes, int n_in,
                              void* d_out, int out_size, void* d_ws, size_t ws_size,
                              hipStream_t stream)
{
  const float* q_n = (const float*)d_in[0];
  const float* q_c = (const float*)d_in[1];
  const int* mask = (const int*)d_in[2];
  const float* W[10];
  for (int i = 0; i < 10; ++i) W[i] = (const float*)d_in[3+i];
  // W[0]=W_query_n W[1]=W_key_nn W[2]=W_val_nn W[3]=W_key_c W[4]=W_val_c
  // W[5]=W_query_c W[6]=W_key_n  W[7]=W_val_n  W[8]=W_out_node W[9]=W_out_color

  uint16_t* ws16 = (uint16_t*)d_ws;
  const size_t PE = (size_t)NH*NF*NK;   // 1,048,576 elements per slot
  uint16_t* Qc   = ws16 + 0*PE;
  uint16_t* Kn   = ws16 + 1*PE;
  uint16_t* VTn  = ws16 + 2*PE;   // [hb][16][1024], n mu-permuted
  uint16_t* Qn   = ws16 + 3*PE;
  uint16_t* Knn  = ws16 + 4*PE;
  uint16_t* VTnn = ws16 + 5*PE;
  uint16_t* Knc  = ws16 + 6*PE;
  uint16_t* VTnc = ws16 + 7*PE;
  uint16_t* heads_node = ws16 + 8*PE;   // [row][h*16+v] bf16
  uint32_t* packN   = (uint32_t*)(ws16 + 9*PE);   // 1 MB
  uint16_t* heads_c = ws16 + 10*PE;     // separate slot: attn z-slices unordered
  uint16_t* onesb   = ws16 + 11*PE;     // 1024 bf16 ones (V^T row 16)

  pack_kernel<<<2048, 256, 0, stream>>>(mask, packN, onesb);

  ProjArgs pa;
  pa.x[0]=q_c; pa.w[0]=W[5];  // Q_c (pre-scaled C2EXP)
  pa.x[1]=q_n; pa.w[1]=W[6];  // K_n
  pa.x[2]=q_n; pa.w[2]=W[7];  // V_n  (transposed, mu-permuted)
  pa.x[3]=q_n; pa.w[3]=W[0];  // Q_n (pre-scaled C2EXP)
  pa.x[4]=q_n; pa.w[4]=W[1];  // K_nn
  pa.x[5]=q_n; pa.w[5]=W[2];  // V_nn (transposed, mu-permuted)
  pa.x[6]=q_c; pa.w[6]=W[3];  // K_nc
  pa.x[7]=q_c; pa.w[7]=W[4];  // V_nc (transposed, mu-permuted)
  proj_kernel<<<dim3(64, 8), 256, 0, stream>>>(pa, ws16);

  attn_kernel<<<dim3(8, 64, 2), 512, 0, stream>>>(
      Qn, Knn, VTnn, Knc, VTnc, Qc, Kn, VTn, packN, onesb,
      heads_node, heads_c);

  outproj_kernel<<<dim3(128, 2), 256, 0, stream>>>(heads_node, heads_c,
                                                   W[8], W[9], (float*)d_out);
}